// Round 10
// baseline (481.057 us; speedup 1.0000x reference)
//
#include <hip/hip_runtime.h>

typedef _Float16 half_t;
typedef __attribute__((ext_vector_type(2))) _Float16 half2v;
typedef __attribute__((ext_vector_type(4))) _Float16 half4;
typedef __attribute__((ext_vector_type(8))) _Float16 half8;
typedef __attribute__((ext_vector_type(4))) float f32x4;

#define BB 32
#define SS 1024
#define DD 768
#define RR 8
#define MM (BB*SS)

// ---------------- workspace layout (float offsets) ----------------
#define OFF_IMP_S 0u
#define OFF_IMP_U 32768u
#define OFF_WI_S  65536u      // 262144
#define OFF_WI_U  327680u     // 262144
#define OFF_REG_S 589824u     // 196608  (R,B,D)
#define OFF_REG_U 786432u     // 196608
#define OFF_AI    983040u     // 196608
#define OFF_BJ    1179648u    // 196608
#define OFF_H2S   2949120u    // 786432
#define OFF_SIM   3735552u    // 64
#define OFF_IDX   3735616u    // 8 (ints)
#define OFF_T1    3932288u    // 196608
#define OFF_PP    4128896u    // 196608
#define OFF_POOL  4325504u    // 196608
#define OFF_FP    4522112u    // 196608 (fallback fuse partials)
#define OFF_WPI   4718720u    // fallback: imp_w1 packed f16
#define OFF_WPC   4866176u    // fallback: clu_w1 packed f16 (ends 5161088)
// ---- big-ws path ----
#define OFF_A16S  5242880u    // f16 sat: 12582912 floats -> ends 17825792
#define OFF_BP    17825792u   // packed W^T f16 [1152][768]: 442368 floats -> ends 18268160
#define OFF_A16U  18268160u   // f16 uav: 12582912 floats -> ends 30851072
#define OFF_PIMP  30851072u   // imp partials [2][3][32768] -> ends 31047680
#define OFF_PCLU  31047680u   // clu partials [2][6][32768][8] = 3145728 -> ends 34193408
#define WS_NEED_FLOATS 37142528u
// after k_post2, pclu region is dead -> reuse for regions partials + fuse partials
#define OFF_RP3   OFF_PCLU                  // 2 x 1572864 -> ends 34193408
#define OFF_DP3   34193408u                 // 2 x 2048 -> ends 34197504
#define OFF_FP24  34197504u                 // 24*32*768 = 589824 -> ends 34787328

// ================== global_load_lds helper (16B, wave dest) ==================
__device__ __forceinline__ void gload16(const half_t* g, half_t* l)
{
    __builtin_amdgcn_global_load_lds(
        (const __attribute__((address_space(1))) void*)g,
        (__attribute__((address_space(3))) void*)l, 16, 0, 0);
}

// ============ f32 -> f16 feature conversion (both sets, one launch) ============
__global__ __launch_bounds__(256)
void k_cvt2(const float* __restrict__ sat, const float* __restrict__ uav,
            half_t* __restrict__ os, half_t* __restrict__ ou)
{
    const int set = blockIdx.x / 3072;
    const int b2 = blockIdx.x - set*3072;
    const float* in = set ? uav : sat;
    half_t* out = set ? ou : os;
    const int base = b2*256 + threadIdx.x;
#pragma unroll
    for (int i = 0; i < 8; i++) {
        const size_t idx4 = (size_t)i*786432 + base;
        const float4 v = *(const float4*)&in[idx4*4];
        half4 h;
        h[0] = (half_t)v.x; h[1] = (half_t)v.y; h[2] = (half_t)v.z; h[3] = (half_t)v.w;
        *(half4*)&out[idx4*4] = h;
    }
}

// ====== pack [imp_w1 | clu_w1] (K x N f32) -> Bp[n][k] f16 transposed ======
__global__ __launch_bounds__(256)
void k_packw(const float* __restrict__ wi1, const float* __restrict__ wc1,
             half_t* __restrict__ bp)
{
    const int id = blockIdx.x*256 + threadIdx.x;   // 221184
    if (id >= 221184) return;
    const int n = id / 192, k0 = (id % 192)*4;
    half4 h;
#pragma unroll
    for (int j = 0; j < 4; j++) {
        const float v = (n < 384) ? wi1[(size_t)(k0+j)*384 + n]
                                  : wc1[(size_t)(k0+j)*768 + (n - 384)];
        h[j] = (half_t)v;
    }
    *(half4*)&bp[(size_t)n*768 + k0] = h;
}

// ===== big GEMM + fused layer-2 partials. BM=256, BK=32, wave tile 128x64. =====
// logical grid: set(2) x mb(128) x nb(9) = 2304 blocks, XCD-swizzled (bijective).
// Same sync structure as round-7/9 verified kernel: gload -> barrier -> read+MFMA -> barrier.
// mfma(b, a) -> acc[mi][ni][q] = C[row0 + wm*128 + mi*16 + l15][n0 + wn*64 + ni*16 + g*4 + q]
__global__ __launch_bounds__(256)
void k_gemm1p(const half_t* __restrict__ A0, const half_t* __restrict__ A1,
              const half_t* __restrict__ Bp,
              const float* __restrict__ b1i, const float* __restrict__ b1c,
              const float* __restrict__ w2i, const float* __restrict__ w2c,
              float* __restrict__ pimp, float* __restrict__ pclu)
{
    __shared__ half_t Als[256*32];        // 16 KB
    __shared__ half_t Bls[128*32];        // 8 KB
    __shared__ float redu[4096];          // 16 KB combine buffer
    const int t = threadIdx.x;
    const int lane = t & 63, wv = t >> 6;
    const int wm = wv >> 1, wn = wv & 1;
    const int l15 = lane & 15, g = lane >> 4;
    const int swz = (l15 >> 1) & 3;

    const int bid = blockIdx.x;
    const int xcd = bid & 7, kk = bid >> 3;
    const int mbh = kk / 9, nb = kk - mbh*9;
    const int mb = mbh*8 + xcd;            // 0..255
    const int set = mb >> 7;
    const int row0 = (mb & 127) * 256;
    const int n0 = nb * 128;
    const half_t* __restrict__ A = set ? A1 : A0;

    f32x4 acc[8][4];
#pragma unroll
    for (int mi = 0; mi < 8; mi++)
#pragma unroll
        for (int ni = 0; ni < 4; ni++)
#pragma unroll
            for (int q = 0; q < 4; q++) acc[mi][ni][q] = 0.f;

    size_t arow[4], brow[2];
#pragma unroll
    for (int i = 0; i < 4; i++) {
        const int u = (i*4 + wv)*64 + lane;          // 0..1023
        const int maj = u >> 2;                      // 0..255
        const int c = (u & 3) ^ ((maj >> 1) & 3);
        arow[i] = (size_t)(row0 + maj)*768 + c*8;
    }
#pragma unroll
    for (int i = 0; i < 2; i++) {
        const int u = (i*4 + wv)*64 + lane;          // 0..511
        const int maj = u >> 2;                      // 0..127
        const int c = (u & 3) ^ ((maj >> 1) & 3);
        brow[i] = (size_t)(n0 + maj)*768 + c*8;
    }

    for (int kt = 0; kt < 24; kt++) {
        const int ko = kt*32;
#pragma unroll
        for (int i = 0; i < 4; i++)
            gload16(A + arow[i] + ko, &Als[(i*4 + wv)*512]);
#pragma unroll
        for (int i = 0; i < 2; i++)
            gload16(Bp + brow[i] + ko, &Bls[(i*4 + wv)*512]);
        __syncthreads();
        half8 a[8], b[4];
#pragma unroll
        for (int mi = 0; mi < 8; mi++) {
            const int maj = wm*128 + mi*16 + l15;
            a[mi] = *(const half8*)&Als[maj*32 + ((g ^ swz) << 3)];
        }
#pragma unroll
        for (int ni = 0; ni < 4; ni++) {
            const int maj = wn*64 + ni*16 + l15;
            b[ni] = *(const half8*)&Bls[maj*32 + ((g ^ swz) << 3)];
        }
#pragma unroll
        for (int mi = 0; mi < 8; mi++)
#pragma unroll
            for (int ni = 0; ni < 4; ni++)
                acc[mi][ni] = __builtin_amdgcn_mfma_f32_16x16x32_f16(
                                  b[ni], a[mi], acc[mi][ni], 0, 0, 0);
        __syncthreads();
    }

    // ------- fused layer-2 partial epilogue -------
    if (nb < 3) {
        f32x4 b1q[4], w2q[4];
#pragma unroll
        for (int ni = 0; ni < 4; ni++) {
            const int c0 = n0 + wn*64 + ni*16 + g*4;
            b1q[ni] = *(const f32x4*)&b1i[c0];
            w2q[ni] = *(const f32x4*)&w2i[c0];
        }
        float pr[8];
#pragma unroll
        for (int mi = 0; mi < 8; mi++) {
            float s = 0.f;
#pragma unroll
            for (int ni = 0; ni < 4; ni++)
#pragma unroll
                for (int q = 0; q < 4; q++)
                    s += fmaxf(acc[mi][ni][q] + b1q[ni][q], 0.f) * w2q[ni][q];
            s += __shfl_xor(s, 16); s += __shfl_xor(s, 32);
            pr[mi] = s;
        }
        if (g == 0) {
#pragma unroll
            for (int mi = 0; mi < 8; mi++)
                redu[(wm*128 + mi*16 + l15)*2 + wn] = pr[mi];
        }
        __syncthreads();
        pimp[(size_t)(set*3 + nb)*32768 + row0 + t] = redu[t*2] + redu[t*2+1];
    } else {
        const int nbc = nb - 3;
        const int colb = n0 - 384 + wn*64 + g*4;
        f32x4 lglo[8], lghi[8];
#pragma unroll
        for (int mi = 0; mi < 8; mi++) {
            lglo[mi] = (f32x4){0.f,0.f,0.f,0.f};
            lghi[mi] = (f32x4){0.f,0.f,0.f,0.f};
        }
#pragma unroll
        for (int ni = 0; ni < 4; ni++) {
            const int c0 = colb + ni*16;
            const f32x4 b1v = *(const f32x4*)&b1c[c0];
#pragma unroll
            for (int q = 0; q < 4; q++) {
                const f32x4 wlo = *(const f32x4*)&w2c[(c0+q)*8];
                const f32x4 whi = *(const f32x4*)&w2c[(c0+q)*8 + 4];
#pragma unroll
                for (int mi = 0; mi < 8; mi++) {
                    const float v = fmaxf(acc[mi][ni][q] + b1v[q], 0.f);
                    lglo[mi] += wlo * v;
                    lghi[mi] += whi * v;
                }
            }
        }
#pragma unroll
        for (int mi = 0; mi < 8; mi++)
#pragma unroll
            for (int e = 0; e < 4; e++) {
                float x = lglo[mi][e];
                x += __shfl_xor(x, 16); x += __shfl_xor(x, 32);
                lglo[mi][e] = x;
                float y = lghi[mi][e];
                y += __shfl_xor(y, 16); y += __shfl_xor(y, 32);
                lghi[mi][e] = y;
            }
        if (g == 0) {
#pragma unroll
            for (int mi = 0; mi < 8; mi++) {
                const int row = wm*128 + mi*16 + l15;   // 0..255
                *(f32x4*)&redu[(row*2 + wn)*8]     = lglo[mi];
                *(f32x4*)&redu[(row*2 + wn)*8 + 4] = lghi[mi];
            }
        }
        __syncthreads();
#pragma unroll
        for (int rr = 0; rr < 2; rr++) {
            const int row = rr*128 + (t >> 1), jh = (t & 1)*4;
            const f32x4 s0 = *(const f32x4*)&redu[(row*2 + 0)*8 + jh];
            const f32x4 s1 = *(const f32x4*)&redu[(row*2 + 1)*8 + jh];
            f32x4 s = s0 + s1;
            *(f32x4*)&pclu[((size_t)(set*6 + nbc)*32768 + row0 + row)*8 + jh] = s;
        }
    }
}

// ==== post2: reduce partials -> imp, softmax(clu logits), wi (both sets) ====
__global__ __launch_bounds__(256)
void k_post2(const float* __restrict__ pimp, const float* __restrict__ pclu,
             const float* __restrict__ b2i, const float* __restrict__ b2c,
             float* __restrict__ wi_s, float* __restrict__ wi_u)
{
    const int gid = blockIdx.x*256 + threadIdx.x;    // 65536
    const int set = gid >> 15, row = gid & 32767;
    const float* pi = pimp + (size_t)set*3*32768;
    const float* pc = pclu + (size_t)set*6*32768*8;
    const float imp = pi[row] + pi[32768 + row] + pi[2*32768 + row] + b2i[0];
    float lg[8];
#pragma unroll
    for (int j = 0; j < 8; j++) lg[j] = b2c[j];
#pragma unroll
    for (int c = 0; c < 6; c++) {
        const float4 a = *(const float4*)&pc[((size_t)c*32768 + row)*8];
        const float4 b = *(const float4*)&pc[((size_t)c*32768 + row)*8 + 4];
        lg[0] += a.x; lg[1] += a.y; lg[2] += a.z; lg[3] += a.w;
        lg[4] += b.x; lg[5] += b.y; lg[6] += b.z; lg[7] += b.w;
    }
    float mx = -1e30f;
#pragma unroll
    for (int j = 0; j < 8; j++) mx = fmaxf(mx, lg[j]);
    float sm = 0.f;
#pragma unroll
    for (int j = 0; j < 8; j++) { lg[j] = expf(lg[j] - mx); sm += lg[j]; }
    const float iv = imp / sm;
    float* wo = set ? wi_u : wi_s;
    float4 o0, o1;
    o0.x = lg[0]*iv; o0.y = lg[1]*iv; o0.z = lg[2]*iv; o0.w = lg[3]*iv;
    o1.x = lg[4]*iv; o1.y = lg[5]*iv; o1.z = lg[6]*iv; o1.w = lg[7]*iv;
    *(float4*)&wo[(size_t)row*8]     = o0;
    *(float4*)&wo[(size_t)row*8 + 4] = o1;
}

// ======= regions phase A (f16 features, 8 s-segments, both sets) =======
__global__ __launch_bounds__(192)
void k_regions_a3(const half_t* __restrict__ fs, const half_t* __restrict__ fu,
                  const float* __restrict__ wis, const float* __restrict__ wiu,
                  float* __restrict__ partb, float* __restrict__ dpartb)
{
    __shared__ float wil[128*8];
    const int t = threadIdx.x;
    const int sseg = blockIdx.x, b = blockIdx.y, zz = blockIdx.z;
    const half_t* f = zz ? fu : fs;
    const float* wi = zz ? wiu : wis;
    float* part  = partb  + (size_t)zz*1572864u;
    float* dpart = dpartb + (size_t)zz*2048u;
    const int s0 = sseg*128;
    for (int l = t; l < 256; l += 192)
        *(float4*)&wil[l*4] = *(const float4*)&wi[((size_t)b*SS + s0)*8 + l*4];
    __syncthreads();
    if (t < 8) {
        float p = 0.f;
        for (int s = 0; s < 128; s++) p += wil[s*8 + t];
        dpart[((size_t)sseg*32 + b)*8 + t] = p;
    }
    f32x4 acc[8];
#pragma unroll
    for (int r = 0; r < 8; r++) acc[r] = (f32x4){0.f,0.f,0.f,0.f};
    const half_t* fp = f + ((size_t)b*SS + s0)*768 + t*4;
#pragma unroll 4
    for (int s = 0; s < 128; s++) {
        const half4 hv = *(const half4*)&fp[(size_t)s*768];
        f32x4 vv;
        vv[0] = (float)hv[0]; vv[1] = (float)hv[1];
        vv[2] = (float)hv[2]; vv[3] = (float)hv[3];
#pragma unroll
        for (int r = 0; r < 8; r++) acc[r] += vv * wil[s*8 + r];
    }
#pragma unroll
    for (int r = 0; r < 8; r++) {
        float4 o; o.x = acc[r][0]; o.y = acc[r][1]; o.z = acc[r][2]; o.w = acc[r][3];
        *(float4*)&part[(((size_t)sseg*8 + r)*32 + b)*768 + t*4] = o;
    }
}

// ====== regions phase B: reg = sum_sseg part / (den+1e-8), both sets ======
__global__ __launch_bounds__(256)
void k_regions_b3(const float* __restrict__ partb, const float* __restrict__ dpartb,
                  float* __restrict__ reg_s, float* __restrict__ reg_u)
{
    __shared__ float dinv_s;
    const int t = threadIdx.x;
    const int zz = blockIdx.y;
    const float* part  = partb  + (size_t)zz*1572864u;
    const float* dpart = dpartb + (size_t)zz*2048u;
    float* reg = zz ? reg_u : reg_s;
    const int r = blockIdx.x >> 5, b = blockIdx.x & 31;
    if (t == 0) {
        float s = 0.f;
        for (int q = 0; q < 8; q++) s += dpart[((size_t)q*32 + b)*8 + r];
        dinv_s = 1.f / (s + 1e-8f);
    }
    __syncthreads();
    const float dinv = dinv_s;
#pragma unroll
    for (int i = 0; i < 3; i++) {
        const int d = t + i*256;
        float s = 0.f;
#pragma unroll
        for (int q = 0; q < 8; q++)
            s += part[(((size_t)q*8 + r)*32 + b)*768 + d];
        reg[((size_t)r*BB + b)*DD + d] = s * dinv;
    }
}

// ====== fp32 GEMM small-M: C = act(A@W + bscale*bias), 32x32 tile ======
__global__ __launch_bounds__(256)
void gemm32(const float* __restrict__ A, int lda,
            const float* __restrict__ W, int ldw,
            const float* __restrict__ bias, float bscale, int do_relu,
            float* __restrict__ C, int ldc, int K)
{
    __shared__ float As[32*36];
    __shared__ float Bs[32*36];
    const int t = threadIdx.x;
    const int row0 = blockIdx.x*32, n0 = blockIdx.y*32;
    const int lr = t >> 3, lc4 = (t & 7)*4;
    float4 acc = make_float4(0.f,0.f,0.f,0.f);
    for (int kt = 0; kt < K; kt += 32) {
        *(float4*)&As[lr*36 + lc4] = *(const float4*)&A[(size_t)(row0+lr)*lda + kt + lc4];
        *(float4*)&Bs[lr*36 + lc4] = *(const float4*)&W[(size_t)(kt+lr)*ldw + n0 + lc4];
        __syncthreads();
#pragma unroll
        for (int k = 0; k < 32; k++) {
            const float a = As[lr*36 + k];
            const float4 b4 = *(const float4*)&Bs[k*36 + lc4];
            acc.x += a*b4.x; acc.y += a*b4.y; acc.z += a*b4.z; acc.w += a*b4.w;
        }
        __syncthreads();
    }
    float4 o = acc;
    if (bias) {
        const float4 b4 = *(const float4*)&bias[n0 + lc4];
        o.x += b4.x*bscale; o.y += b4.y*bscale; o.z += b4.z*bscale; o.w += b4.w*bscale;
    }
    if (do_relu) {
        o.x = fmaxf(o.x,0.f); o.y = fmaxf(o.y,0.f);
        o.z = fmaxf(o.z,0.f); o.w = fmaxf(o.w,0.f);
    }
    *(float4*)&C[(size_t)(row0+lr)*ldc + n0 + lc4] = o;
}

// ====== Ai/Bj batched: z=0: C0 = A0@W + b ; z=1: C1 = A1@(W+768*768) ======
__global__ __launch_bounds__(256)
void gemm32z(const float* __restrict__ A0, const float* __restrict__ A1,
             const float* __restrict__ W, const float* __restrict__ bias,
             float* __restrict__ C0, float* __restrict__ C1)
{
    __shared__ float As[32*36];
    __shared__ float Bs[32*36];
    const int t = threadIdx.x;
    const int zz = blockIdx.z;
    const float* A = zz ? A1 : A0;
    const float* Wp = W + (size_t)zz*768*768;
    float* C = zz ? C1 : C0;
    const int row0 = blockIdx.x*32, n0 = blockIdx.y*32;
    const int lr = t >> 3, lc4 = (t & 7)*4;
    float4 acc = make_float4(0.f,0.f,0.f,0.f);
    for (int kt = 0; kt < 768; kt += 32) {
        *(float4*)&As[lr*36 + lc4] = *(const float4*)&A[(size_t)(row0+lr)*768 + kt + lc4];
        *(float4*)&Bs[lr*36 + lc4] = *(const float4*)&Wp[(size_t)(kt+lr)*768 + n0 + lc4];
        __syncthreads();
#pragma unroll
        for (int k = 0; k < 32; k++) {
            const float a = As[lr*36 + k];
            const float4 b4 = *(const float4*)&Bs[k*36 + lc4];
            acc.x += a*b4.x; acc.y += a*b4.y; acc.z += a*b4.z; acc.w += a*b4.w;
        }
        __syncthreads();
    }
    float4 o = acc;
    if (zz == 0) {
        const float4 b4 = *(const float4*)&bias[n0 + lc4];
        o.x += b4.x; o.y += b4.y; o.z += b4.z; o.w += b4.w;
    }
    *(float4*)&C[(size_t)(row0+lr)*768 + n0 + lc4] = o;
}

// ====== h2 fused: h2 = relu( relu(Ai[i]+Bj[j]) @ sim_w2 + b2 ), h1 on the fly ======
__global__ __launch_bounds__(256)
void k_h2f(const float* __restrict__ Ai, const float* __restrict__ Bj,
           const float* __restrict__ W, const float* __restrict__ bias,
           float* __restrict__ C)
{
    __shared__ float As[32*36];
    __shared__ float Bs[32*36];
    const int t = threadIdx.x;
    const int ij = blockIdx.x, n0 = blockIdx.y*32;
    const int i = ij >> 3, j = ij & 7;
    const int lr = t >> 3, lc4 = (t & 7)*4;
    float4 acc = make_float4(0.f,0.f,0.f,0.f);
    for (int kt = 0; kt < 768; kt += 32) {
        const float4 a4 = *(const float4*)&Ai[(size_t)(i*32+lr)*768 + kt + lc4];
        const float4 b4 = *(const float4*)&Bj[(size_t)(j*32+lr)*768 + kt + lc4];
        float4 h1v;
        h1v.x = fmaxf(a4.x + b4.x, 0.f); h1v.y = fmaxf(a4.y + b4.y, 0.f);
        h1v.z = fmaxf(a4.z + b4.z, 0.f); h1v.w = fmaxf(a4.w + b4.w, 0.f);
        *(float4*)&As[lr*36 + lc4] = h1v;
        *(float4*)&Bs[lr*36 + lc4] = *(const float4*)&W[(size_t)(kt+lr)*384 + n0 + lc4];
        __syncthreads();
#pragma unroll
        for (int k = 0; k < 32; k++) {
            const float a = As[lr*36 + k];
            const float4 w4 = *(const float4*)&Bs[k*36 + lc4];
            acc.x += a*w4.x; acc.y += a*w4.y; acc.z += a*w4.z; acc.w += a*w4.w;
        }
        __syncthreads();
    }
    const float4 bb = *(const float4*)&bias[n0 + lc4];
    float4 o;
    o.x = fmaxf(acc.x + bb.x, 0.f); o.y = fmaxf(acc.y + bb.y, 0.f);
    o.z = fmaxf(acc.z + bb.z, 0.f); o.w = fmaxf(acc.w + bb.w, 0.f);
    *(float4*)&C[(size_t)(ij*32+lr)*384 + n0 + lc4] = o;
}

// ====== attn-V fused: t1 = (rs[r]+ru[idx[r]]) @ attn_wv + 2*bv ======
__global__ __launch_bounds__(256)
void k_zwv(const float* __restrict__ rs, const float* __restrict__ ru,
           const int* __restrict__ idx, const float* __restrict__ W,
           const float* __restrict__ bias, float* __restrict__ C)
{
    __shared__ float As[32*36];
    __shared__ float Bs[32*36];
    const int t = threadIdx.x;
    const int r = blockIdx.x, n0 = blockIdx.y*32;
    const int ir = idx[r];
    const int lr = t >> 3, lc4 = (t & 7)*4;
    float4 acc = make_float4(0.f,0.f,0.f,0.f);
    for (int kt = 0; kt < 768; kt += 32) {
        const float4 a4 = *(const float4*)&rs[(size_t)(r*32+lr)*768 + kt + lc4];
        const float4 b4 = *(const float4*)&ru[(size_t)(ir*32+lr)*768 + kt + lc4];
        float4 z4;
        z4.x = a4.x + b4.x; z4.y = a4.y + b4.y;
        z4.z = a4.z + b4.z; z4.w = a4.w + b4.w;
        *(float4*)&As[lr*36 + lc4] = z4;
        *(float4*)&Bs[lr*36 + lc4] = *(const float4*)&W[(size_t)(kt+lr)*768 + n0 + lc4];
        __syncthreads();
#pragma unroll
        for (int k = 0; k < 32; k++) {
            const float a = As[lr*36 + k];
            const float4 w4 = *(const float4*)&Bs[k*36 + lc4];
            acc.x += a*w4.x; acc.y += a*w4.y; acc.z += a*w4.z; acc.w += a*w4.w;
        }
        __syncthreads();
    }
    const float4 bb = *(const float4*)&bias[n0 + lc4];
    float4 o;
    o.x = acc.x + 2.f*bb.x; o.y = acc.y + 2.f*bb.y;
    o.z = acc.z + 2.f*bb.z; o.w = acc.w + 2.f*bb.w;
    *(float4*)&C[(size_t)(r*32+lr)*768 + n0 + lc4] = o;
}

// =================== FALLBACK path (round-2 kernels) ===================
__global__ __launch_bounds__(256)
void k_pack(const float* __restrict__ wsrc, half_t* __restrict__ p, int KT, int NT)
{
    const int u = blockIdx.x*256 + threadIdx.x;
    const int per_kt = NT*64;
    if (u >= KT*per_kt) return;
    const int kt = u / per_kt, rem = u % per_kt;
    const int nt = rem >> 6, lane = rem & 63;
    const int N = NT*16;
    const int k0 = kt*16 + ((lane>>4)<<2), n = nt*16 + (lane & 15);
    half4 hq;
#pragma unroll
    for (int j = 0; j < 4; j++) hq[j] = (half_t)wsrc[(size_t)(k0+j)*N + n];
    *(half4*)&p[(size_t)u*4] = hq;
}

__global__ __launch_bounds__(256)
void k_imp_mfma(const float* __restrict__ f, const half_t* __restrict__ wp,
                const float* __restrict__ b1, const float* __restrict__ w2,
                const float* __restrict__ b2, float* __restrict__ imp_out)
{
    __shared__ half_t Wb[24*64*4];
    __shared__ half_t Ab[2*64*4];
    __shared__ float red[4][32];
    const int t = threadIdx.x;
    const int w = t >> 6, lane = t & 63;
    const int row0 = blockIdx.x * 32;
    const float4* wp4 = (const float4*)wp;
    f32x4 acc[2][6];
#pragma unroll
    for (int m = 0; m < 2; m++)
#pragma unroll
        for (int i = 0; i < 6; i++)
#pragma unroll
            for (int q = 0; q < 4; q++) acc[m][i][q] = 0.f;
    const int arow = t >> 2, akg = t & 3;
    const float* fA = f + (size_t)(row0 + arow)*768;
    float4 wreg[3]; float4 areg;
#pragma unroll
    for (int i = 0; i < 3; i++) wreg[i] = wp4[i*256 + t];
    if (t < 128) areg = *(const float4*)&fA[akg*4];
    for (int kt = 0; kt < 48; kt++) {
#pragma unroll
        for (int i = 0; i < 3; i++) *(float4*)&Wb[(i*256 + t)*8] = wreg[i];
        if (t < 128) {
            half4 ah;
            ah[0] = (half_t)areg.x; ah[1] = (half_t)areg.y;
            ah[2] = (half_t)areg.z; ah[3] = (half_t)areg.w;
            *(half4*)&Ab[(((arow>>4)<<6) + (akg<<4) + (arow & 15))*4] = ah;
        }
        __syncthreads();
        if (kt < 47) {
#pragma unroll
            for (int i = 0; i < 3; i++) wreg[i] = wp4[(kt+1)*768 + i*256 + t];
            if (t < 128) areg = *(const float4*)&fA[(kt+1)*16 + akg*4];
        }
        half4 a0 = *(half4*)&Ab[lane*4];
        half4 a1 = *(half4*)&Ab[(64 + lane)*4];
#pragma unroll
        for (int i = 0; i < 6; i++) {
            half4 bf = *(half4*)&Wb[((w*6 + i)*64 + lane)*4];
            acc[0][i] = __builtin_amdgcn_mfma_f32_16x16x16f16(a0, bf, acc[0][i], 0, 0, 0);
            acc[1][i] = __builtin_amdgcn_mfma_f32_16x16x16f16(a1, bf, acc[1][i], 0, 0, 0);
        }
        __syncthreads();
    }
    float b1v[6], w2v[6];
#pragma unroll
    for (int i = 0; i < 6; i++) {
        const int col = (w*6 + i)*16 + (lane & 15);
        b1v[i] = b1[col]; w2v[i] = w2[col];
    }
#pragma unroll
    for (int m = 0; m < 2; m++)
#pragma unroll
        for (int r = 0; r < 4; r++) {
            float s = 0.f;
#pragma unroll
            for (int i = 0; i < 6; i++)
                s += fmaxf(acc[m][i][r] + b1v[i], 0.f) * w2v[i];
            s += __shfl_xor(s,1); s += __shfl_xor(s,2);
            s += __shfl_xor(s,4); s += __shfl_xor(s,8);
            if ((lane & 15) == 0) red[w][m*16 + ((lane>>4)<<2) + r] = s;
        }
    __syncthreads();
    if (t < 32)
        imp_out[row0 + t] = red[0][t] + red[1][t] + red[2][t] + red[3][t] + b2[0];
}

__global__ __launch_bounds__(256)
void k_clu_mfma(const float* __restrict__ f, const half_t* __restrict__ wp,
                const float* __restrict__ b1, const float* __restrict__ w2,
                const float* __restrict__ b2, const float* __restrict__ imp,
                float* __restrict__ wi_out)
{
    __shared__ half_t Wb[48*64*4];
    __shared__ half_t Ab[2*64*4];
    __shared__ float red[4][32][8];
    const int t = threadIdx.x;
    const int w = t >> 6, lane = t & 63;
    const int row0 = blockIdx.x * 32;
    const float4* wp4 = (const float4*)wp;
    f32x4 acc[2][12];
#pragma unroll
    for (int m = 0; m < 2; m++)
#pragma unroll
        for (int i = 0; i < 12; i++)
#pragma unroll
            for (int q = 0; q < 4; q++) acc[m][i][q] = 0.f;
    const int arow = t >> 2, akg = t & 3;
    const float* fA = f + (size_t)(row0 + arow)*768;
    float4 wreg[6]; float4 areg;
#pragma unroll
    for (int i = 0; i < 6; i++) wreg[i] = wp4[i*256 + t];
    if (t < 128) areg = *(const float4*)&fA[akg*4];
    for (int kt = 0; kt < 48; kt++) {
#pragma unroll
        for (int i = 0; i < 6; i++) *(float4*)&Wb[(i*256 + t)*8] = wreg[i];
        if (t < 128) {
            half4 ah;
            ah[0] = (half_t)areg.x; ah[1] = (half_t)areg.y;
            ah[2] = (half_t)areg.z; ah[3] = (half_t)areg.w;
            *(half4*)&Ab[(((arow>>4)<<6) + (akg<<4) + (arow & 15))*4] = ah;
        }
        __syncthreads();
        if (kt < 47) {
#pragma unroll
            for (int i = 0; i < 6; i++) wreg[i] = wp4[(kt+1)*1536 + i*256 + t];
            if (t < 128) areg = *(const float4*)&fA[(kt+1)*16 + akg*4];
        }
        half4 a0 = *(half4*)&Ab[lane*4];
        half4 a1 = *(half4*)&Ab[(64 + lane)*4];
#pragma unroll
        for (int i = 0; i < 12; i++) {
            half4 bf = *(half4*)&Wb[((w*12 + i)*64 + lane)*4];
            acc[0][i] = __builtin_amdgcn_mfma_f32_16x16x16f16(a0, bf, acc[0][i], 0, 0, 0);
            acc[1][i] = __builtin_amdgcn_mfma_f32_16x16x16f16(a1, bf, acc[1][i], 0, 0, 0);
        }
        __syncthreads();
    }
    float b1v[12];
#pragma unroll
    for (int i = 0; i < 12; i++) b1v[i] = b1[(w*12 + i)*16 + (lane & 15)];
#pragma unroll
    for (int h = 0; h < 2; h++) {
        float lg[2][4][4];
#pragma unroll
        for (int m = 0; m < 2; m++)
#pragma unroll
            for (int r = 0; r < 4; r++)
#pragma unroll
                for (int q = 0; q < 4; q++) lg[m][r][q] = 0.f;
#pragma unroll
        for (int i = 0; i < 12; i++) {
            const int col = (w*12 + i)*16 + (lane & 15);
            const float4 w2v = *(const float4*)&w2[col*8 + h*4];
#pragma unroll
            for (int m = 0; m < 2; m++)
#pragma unroll
                for (int r = 0; r < 4; r++) {
                    const float v = fmaxf(acc[m][i][r] + b1v[i], 0.f);
                    lg[m][r][0] += v*w2v.x; lg[m][r][1] += v*w2v.y;
                    lg[m][r][2] += v*w2v.z; lg[m][r][3] += v*w2v.w;
                }
        }
#pragma unroll
        for (int m = 0; m < 2; m++)
#pragma unroll
            for (int r = 0; r < 4; r++)
#pragma unroll
                for (int q = 0; q < 4; q++) {
                    float s = lg[m][r][q];
                    s += __shfl_xor(s,1); s += __shfl_xor(s,2);
                    s += __shfl_xor(s,4); s += __shfl_xor(s,8);
                    if ((lane & 15) == 0)
                        red[w][m*16 + ((lane>>4)<<2) + r][h*4 + q] = s;
                }
    }
    __syncthreads();
    if (t < 32) {
        float l8[8], mx = -1e30f;
#pragma unroll
        for (int r8 = 0; r8 < 8; r8++) {
            l8[r8] = red[0][t][r8] + red[1][t][r8] + red[2][t][r8] + red[3][t][r8] + b2[r8];
            mx = fmaxf(mx, l8[r8]);
        }
        float s = 0.f;
#pragma unroll
        for (int r8 = 0; r8 < 8; r8++) { l8[r8] = expf(l8[r8] - mx); s += l8[r8]; }
        const float iv = imp[row0 + t] / s;
#pragma unroll
        for (int r8 = 0; r8 < 8; r8++) wi_out[(row0 + t)*8 + r8] = l8[r8] * iv;
    }
}

__global__ __launch_bounds__(256)
void k_regions(const float* __restrict__ f, const float* __restrict__ wi,
               float* __restrict__ reg)
{
    __shared__ float wil[SS*8];
    __shared__ float pden[64];
    __shared__ float dinv[8];
    __shared__ float pacc[256*8];
    const int t = threadIdx.x, b = blockIdx.x, dc = blockIdx.y;
    for (int l = t; l < SS*8; l += 256) wil[l] = wi[(size_t)b*SS*8 + l];
    __syncthreads();
    if (t < 64) {
        const int r = t & 7, seg = t >> 3;
        float p = 0.f;
        for (int s = seg*128; s < seg*128 + 128; s++) p += wil[s*8 + r];
        pden[t] = p;
    }
    __syncthreads();
    if (t < 8) {
        float dsum = 0.f;
        for (int g = 0; g < 8; g++) dsum += pden[g*8 + t];
        dinv[t] = 1.f / (dsum + 1e-8f);
    }
    const int dl = t & 63, sseg = t >> 6;
    const int d = dc*64 + dl;
    float acc[8] = {0,0,0,0,0,0,0,0};
    const float* fp = f + (size_t)b*SS*DD + d;
    for (int s = sseg*256; s < (sseg+1)*256; s++) {
        const float v = fp[(size_t)s*DD];
        const float4 w0 = *(const float4*)&wil[s*8];
        const float4 w1 = *(const float4*)&wil[s*8 + 4];
        acc[0] += v*w0.x; acc[1] += v*w0.y; acc[2] += v*w0.z; acc[3] += v*w0.w;
        acc[4] += v*w1.x; acc[5] += v*w1.y; acc[6] += v*w1.z; acc[7] += v*w1.w;
    }
#pragma unroll
    for (int r = 0; r < 8; r++) pacc[t*8 + r] = acc[r];
    __syncthreads();
    if (t < 64) {
#pragma unroll
        for (int r = 0; r < 8; r++) {
            const float s = pacc[(0*64+t)*8+r] + pacc[(1*64+t)*8+r]
                          + pacc[(2*64+t)*8+r] + pacc[(3*64+t)*8+r];
            reg[((size_t)r*BB + b)*DD + dc*64 + t] = s * dinv[r];
        }
    }
}

// ========== sim[i,j] = mean_b sigmoid(h2[i,j,b,:] @ w3 + b3) ==========
__global__ __launch_bounds__(256)
void k_sim(const float* __restrict__ h2, const float* __restrict__ w3,
           const float* __restrict__ b3, float* __restrict__ sim)
{
    __shared__ float sv[32];
    const int t = threadIdx.x, ij = blockIdx.x;
    const int b = t >> 3, g = t & 7;
    const float* row = h2 + (size_t)(ij*32 + b)*384;
    float p = 0.f;
    for (int c = g*48; c < g*48 + 48; c++) p += row[c]*w3[c];
    p += __shfl_xor(p,1); p += __shfl_xor(p,2); p += __shfl_xor(p,4);
    if (g == 0) sv[b] = 1.f/(1.f + expf(-(p + b3[0])));
    __syncthreads();
    if (t == 0) {
        float m = 0.f;
        for (int i = 0; i < 32; i++) m += sv[i];
        sim[ij] = m / 32.f;
    }
}

__global__ void k_match(const float* __restrict__ sim, int* __restrict__ idx)
{
    if (threadIdx.x == 0) {
        bool used[8] = {false,false,false,false,false,false,false,false};
        for (int i = 0; i < 8; i++) {
            float m = -2.f; int jj = 0;
            for (int j = 0; j < 8; j++) {
                const float s = used[j] ? -1.f : sim[i*8 + j];
                if (s > m) { m = s; jj = j; }
            }
            idx[i] = jj; used[jj] = true;
        }
    }
}

__device__ __forceinline__ float block_sum_256(float v, float* red)
{
#pragma unroll
    for (int m = 1; m < 64; m <<= 1) v += __shfl_xor(v, m);
    const int t = threadIdx.x;
    __syncthreads();
    if ((t & 63) == 0) red[t >> 6] = v;
    __syncthreads();
    return red[0] + red[1] + red[2] + red[3];
}

__global__ __launch_bounds__(256)
void k_ln(const float* __restrict__ x, const float* __restrict__ g,
          const float* __restrict__ bta, float* __restrict__ y)
{
    __shared__ float red[4];
    const int row = blockIdx.x, t = threadIdx.x;
    float v[3];
#pragma unroll
    for (int i = 0; i < 3; i++) v[i] = x[(size_t)row*768 + t + i*256];
    float s = v[0] + v[1] + v[2];
    s = block_sum_256(s, red);
    const float m = s / 768.f;
    float q = 0.f;
#pragma unroll
    for (int i = 0; i < 3; i++) { const float d = v[i]-m; q += d*d; }
    q = block_sum_256(q, red);
    const float inv = rsqrtf(q/768.f + 1e-5f);
#pragma unroll
    for (int i = 0; i < 3; i++) {
        const int c = t + i*256;
        y[(size_t)row*768 + c] = (v[i]-m)*inv*g[c] + bta[c];
    }
}

// ============== fuse GEMM split-K 8 (fallback) =========
__global__ __launch_bounds__(256)
void k_fuse_gemm(const float* __restrict__ pool, const float* __restrict__ fw,
                 float* __restrict__ part)
{
    __shared__ float As[32*20];
    __shared__ float Ws[16*64];
    const int t = threadIdx.x;
    const int cg = t & 15, rg = t >> 4;
    const int kc = blockIdx.x, nb = blockIdx.y;
    float acc[2][4];
#pragma unroll
    for (int r = 0; r < 2; r++)
#pragma unroll
        for (int j = 0; j < 4; j++) acc[r][j] = 0.f;
    for (int kt = 0; kt < 768; kt += 16) {
        if (t < 128) {
            const int k4 = (t & 3)*4, r = t >> 2;
            *(float4*)&As[r*20 + k4] = *(const float4*)&pool[(size_t)(kc*32 + r)*768 + kt + k4];
        }
        {
            const int nq = (t & 15)*4, k = t >> 4;
            *(float4*)&Ws[k*64 + nq] = *(const float4*)&fw[(size_t)(kc*768 + kt + k)*768 + nb*64 + nq];
        }
        __syncthreads();
#pragma unroll
        for (int k = 0; k < 16; k++) {
            const float4 w = *(const float4*)&Ws[k*64 + cg*4];
            const float a0 = As[(rg*2+0)*20+k], a1 = As[(rg*2+1)*20+k];
            acc[0][0]+=a0*w.x; acc[0][1]+=a0*w.y; acc[0][2]+=a0*w.z; acc[0][3]+=a0*w.w;
            acc[1][0]+=a1*w.x; acc[1][1]+=a1*w.y; acc[1][2]+=a1*w.z; acc[1][3]+=a1*w.w;
        }
        __syncthreads();
    }
#pragma unroll
    for (int r = 0; r < 2; r++) {
        float4 o; o.x = acc[r][0]; o.y = acc[r][1]; o.z = acc[r][2]; o.w = acc[r][3];
        *(float4*)&part[(size_t)(kc*32 + rg*2 + r)*768 + nb*64 + cg*4] = o;
    }
}

__global__ __launch_bounds__(256)
void k_fuse_final(const float* __restrict__ part, const float* __restrict__ fb,
                  const float* __restrict__ g, const float* __restrict__ bta,
                  float* __restrict__ out)
{
    __shared__ float red[4];
    const int b = blockIdx.x, t = threadIdx.x;
    float v[3];
#pragma unroll
    for (int i = 0; i < 3; i++) {
        const int c = t + i*256;
        float s = 0.f;
#pragma unroll
        for (int kc = 0; kc < 8; kc++) s += part[(size_t)(kc*32 + b)*768 + c];
        v[i] = s + fb[c];
    }
    float s = v[0] + v[1] + v[2];
    s = block_sum_256(s, red);
    const float m = s / 768.f;
    float q = 0.f;
#pragma unroll
    for (int i = 0; i < 3; i++) { const float d = v[i]-m; q += d*d; }
    q = block_sum_256(q, red);
    const float inv = rsqrtf(q/768.f + 1e-5f);
#pragma unroll
    for (int i = 0; i < 3; i++) {
        const int c = t + i*256;
        out[(size_t)b*768 + c] = fmaxf((v[i]-m)*inv*g[c] + bta[c], 0.f);
    }
}

// ============== fuse GEMM split-K 24 (big path) =========
__global__ __launch_bounds__(256)
void k_fuse_gemm24(const float* __restrict__ pool, const float* __restrict__ fw,
                   float* __restrict__ part)
{
    __shared__ float As[32*20];
    __shared__ float Ws[16*64];
    const int t = threadIdx.x;
    const int cg = t & 15, rg = t >> 4;
    const int kc = blockIdx.x, nb = blockIdx.y;
    const int rr = kc / 3, d0 = (kc % 3) * 256;
    float acc[2][4];
#pragma unroll
    for (int r = 0; r < 2; r++)
#pragma unroll
        for (int j = 0; j < 4; j++) acc[r][j] = 0.f;
    for (int kt = 0; kt < 256; kt += 16) {
        if (t < 128) {
            const int k4 = (t & 3)*4, r = t >> 2;
            *(float4*)&As[r*20 + k4] = *(const float4*)&pool[(size_t)(rr*32 + r)*768 + d0 + kt + k4];
        }
        {
            const int nq = (t & 15)*4, k = t >> 4;
            *(float4*)&Ws[k*64 + nq] = *(const float4*)&fw[(size_t)(rr*768 + d0 + kt + k)*768 + nb*64 + nq];
        }
        __syncthreads();
#pragma unroll
        for (int k = 0; k < 16; k++) {
            const float4 w = *(const float4*)&Ws[k*64 + cg*4];
            const float a0 = As[(rg*2+0)*20+k], a1 = As[(rg*2+1)*20+k];
            acc[0][0]+=a0*w.x; acc[0][1]+=a0*w.y; acc[0][2]+=a0*w.z; acc[0][3]+=a0*w.w;
            acc[1][0]+=a1*w.x; acc[1][1]+=a1*w.y; acc[1][2]+=a1*w.z; acc[1][3]+=a1*w.w;
        }
        __syncthreads();
    }
#pragma unroll
    for (int r = 0; r < 2; r++) {
        float4 o; o.x = acc[r][0]; o.y = acc[r][1]; o.z = acc[r][2]; o.w = acc[r][3];
        *(float4*)&part[(size_t)(kc*32 + rg*2 + r)*768 + nb*64 + cg*4] = o;
    }
}

__global__ __launch_bounds__(256)
void k_fuse_final24(const float* __restrict__ part, const float* __restrict__ fb,
                    const float* __restrict__ g, const float* __restrict__ bta,
                    float* __restrict__ out)
{
    __shared__ float red[4];
    const int b = blockIdx.x, t = threadIdx.x;
    float v[3];
#pragma unroll
    for (int i = 0; i < 3; i++) {
        const int c = t + i*256;
        float s = 0.f;
#pragma unroll
        for (int kc = 0; kc < 24; kc++) s += part[(size_t)(kc*32 + b)*768 + c];
        v[i] = s + fb[c];
    }
    float s = v[0] + v[1] + v[2];
    s = block_sum_256(s, red);
    const float m = s / 768.f;
    float q = 0.f;
#pragma unroll
    for (int i = 0; i < 3; i++) { const float d = v[i]-m; q += d*d; }
    q = block_sum_256(q, red);
    const float inv = rsqrtf(q/768.f + 1e-5f);
#pragma unroll
    for (int i = 0; i < 3; i++) {
        const int c = t + i*256;
        out[(size_t)b*768 + c] = fmaxf((v[i]-m)*inv*g[c] + bta[c], 0.f);
    }
}

// ============================== launcher ==============================
extern "C" void kernel_launch(void* const* d_in, const int* in_sizes, int n_in,
                              void* d_out, int out_size, void* d_ws, size_t ws_size,
                              hipStream_t stream)
{
    (void)in_sizes; (void)n_in; (void)out_size;
    const float* sat     = (const float*)d_in[0];
    const float* uav     = (const float*)d_in[1];
    const float* imp_w1  = (const float*)d_in[2];
    const float* imp_b1  = (const float*)d_in[3];
    const float* imp_w2  = (const float*)d_in[4];
    const float* imp_b2  = (const float*)d_in[5];
    const float* clu_w1  = (const float*)d_in[6];
    const float* clu_b1  = (const float*)d_in[7];
    const float* clu_w2  = (const float*)d_in[8];
    const float* clu_b2  = (const float*)d_in[9];
    const float* sim_w1  = (const float*)d_in[10];
    const float* sim_b1  = (const float*)d_in[11];
    const float* sim_w2  = (const float*)d_in[12];
    const float* sim_b2  = (const float*)d_in[13];
    const float* sim_w3  = (const float*)d_in[14];
    const float* sim_b3  = (const float*)d_in[15];
    const float* attn_wv = (const float*)d_in[16];
    const float* attn_bv = (const float*)d_in[17];
    const float* attn_wo = (const float*)d_in[18];
    const float* attn_bo = (const float*)d_in[19];
    const float* pool_g  = (const float*)d_in[20];
    const float* pool_b  = (const float*)d_in[21];
    const float* fuse_w  = (const float*)d_in[22];
    const float* fuse_b  = (const float*)d_in[23];
    const float* fuse_g  = (const float*)d_in[24];
    const float* fuse_bt = (const float*)d_in[25];
    float* ws  = (float*)d_ws;
    float* out = (float*)d_out;

    const bool big = (ws_size >= (size_t)WS_NEED_FLOATS * 4u);
    if (big) {
        half_t* a16s = (half_t*)(ws + OFF_A16S);
        half_t* a16u = (half_t*)(ws + OFF_A16U);
        half_t* bp   = (half_t*)(ws + OFF_BP);

        k_packw<<<864, 256, 0, stream>>>(imp_w1, clu_w1, bp);
        k_cvt2<<<6144, 256, 0, stream>>>(sat, uav, a16s, a16u);
        k_gemm1p<<<2304, 256, 0, stream>>>(a16s, a16u, bp, imp_b1, clu_b1,
                                           imp_w2, clu_w2,
                                           ws + OFF_PIMP, ws + OFF_PCLU);
        k_post2<<<256, 256, 0, stream>>>(ws + OFF_PIMP, ws + OFF_PCLU,
                                         imp_b2, clu_b2,
                                         ws + OFF_WI_S, ws + OFF_WI_U);
        k_regions_a3<<<dim3(8,32,2), 192, 0, stream>>>(a16s, a16u,
                                                       ws + OFF_WI_S, ws + OFF_WI_U,
                                                       ws + OFF_RP3, ws + OFF_DP3);
        k_regions_b3<<<dim3(256,2), 256, 0, stream>>>(ws + OFF_RP3, ws + OFF_DP3,
                                                      ws + OFF_REG_S, ws + OFF_REG_U);
    } else {
        half_t* wpi = (half_t*)(ws + OFF_WPI);
        half_t* wpc = (half_t*)(ws + OFF_WPC);
        k_pack<<<288, 256, 0, stream>>>(imp_w1, wpi, 48, 24);
        k_pack<<<576, 256, 0, stream>>>(clu_w1, wpc, 48, 48);
        k_imp_mfma<<<1024, 256, 0, stream>>>(sat, wpi, imp_b1, imp_w2, imp_b2, ws + OFF_IMP_S);
        k_imp_mfma<<<1024, 256, 0, stream>>>(uav, wpi, imp_b1, imp_w2, imp_b2, ws + OFF_IMP_U);
        k_clu_mfma<<<1024, 256, 0, stream>>>(sat, wpc, clu_b1, clu_w2, clu_b2, ws + OFF_IMP_S, ws + OFF_WI_S);
        k_clu_mfma<<<1024, 256, 0, stream>>>(uav, wpc, clu_b1, clu_w2, clu_b2, ws + OFF_IMP_U, ws + OFF_WI_U);
        k_regions<<<dim3(32,12), 256, 0, stream>>>(sat, ws + OFF_WI_S, ws + OFF_REG_S);
        k_regions<<<dim3(32,12), 256, 0, stream>>>(uav, ws + OFF_WI_U, ws + OFF_REG_U);
    }

    // similarity MLP: Ai/Bj batched, then fused h1->h2 GEMM, sim, match
    gemm32z<<<dim3(8,24,2), 256, 0, stream>>>(ws + OFF_REG_S, ws + OFF_REG_U,
                                              sim_w1, sim_b1,
                                              ws + OFF_AI, ws + OFF_BJ);
    k_h2f<<<dim3(64,12), 256, 0, stream>>>(ws + OFF_AI, ws + OFF_BJ,
                                           sim_w2, sim_b2, ws + OFF_H2S);
    k_sim<<<64, 256, 0, stream>>>(ws + OFF_H2S, sim_w3, sim_b3, ws + OFF_SIM);
    k_match<<<1, 64, 0, stream>>>(ws + OFF_SIM, (int*)(ws + OFF_IDX));

    // attention pooling: fused z+Wv GEMM, then Wo GEMM, then LN
    k_zwv<<<dim3(8,24), 256, 0, stream>>>(ws + OFF_REG_S, ws + OFF_REG_U,
                                          (const int*)(ws + OFF_IDX),
                                          attn_wv, attn_bv, ws + OFF_T1);
    gemm32<<<dim3(8,24), 256, 0, stream>>>(ws + OFF_T1, 768, attn_wo, 768,
                                           attn_bo, 2.f, 0, ws + OFF_PP, 768, 768);
    k_ln<<<256, 256, 0, stream>>>(ws + OFF_PP, pool_g, pool_b, ws + OFF_POOL);

    // fuse: cat(B, R*D) @ fuse_w -> LN -> relu
    if (big) {
        k_fuse_gemm24<<<dim3(24,12), 256, 0, stream>>>(ws + OFF_POOL, fuse_w, ws + OFF_FP24);
        k_fuse_final24<<<32, 256, 0, stream>>>(ws + OFF_FP24, fuse_b, fuse_g, fuse_bt, out);
    } else {
        k_fuse_gemm<<<dim3(8,12), 256, 0, stream>>>(ws + OFF_POOL, fuse_w, ws + OFF_FP);
        k_fuse_final<<<32, 256, 0, stream>>>(ws + OFF_FP, fuse_b, fuse_g, fuse_bt, out);
    }
}

// Round 11
// 413.053 us; speedup vs baseline: 1.1646x; 1.1646x over previous
//
#include <hip/hip_runtime.h>

typedef _Float16 half_t;
typedef __attribute__((ext_vector_type(2))) _Float16 half2v;
typedef __attribute__((ext_vector_type(4))) _Float16 half4;
typedef __attribute__((ext_vector_type(8))) _Float16 half8;
typedef __attribute__((ext_vector_type(4))) float f32x4;

#define BB 32
#define SS 1024
#define DD 768
#define RR 8
#define MM (BB*SS)

// ---------------- workspace layout (float offsets) ----------------
#define OFF_IMP_S 0u
#define OFF_IMP_U 32768u
#define OFF_WI_S  65536u      // 262144
#define OFF_WI_U  327680u     // 262144
#define OFF_REG_S 589824u     // 196608  (R,B,D)
#define OFF_REG_U 786432u     // 196608
#define OFF_AI    983040u     // 196608
#define OFF_BJ    1179648u    // 196608
#define OFF_H2S   2949120u    // 786432
#define OFF_SIM   3735552u    // 64
#define OFF_IDX   3735616u    // 8 (ints)
#define OFF_T1    3932288u    // 196608
#define OFF_PP    4128896u    // 196608
#define OFF_POOL  4325504u    // 196608
#define OFF_FP    4522112u    // 196608 (fallback fuse partials)
#define OFF_WPI   4718720u    // fallback: imp_w1 packed f16
#define OFF_WPC   4866176u    // fallback: clu_w1 packed f16 (ends 5161088)
// ---- big-ws path ----
#define OFF_A16S  5242880u    // f16 sat: 12582912 floats -> ends 17825792
#define OFF_BP    17825792u   // packed W^T f16 [1152][768]: 442368 floats -> ends 18268160
#define OFF_A16U  18268160u   // f16 uav: 12582912 floats -> ends 30851072
#define OFF_PIMP  30851072u   // imp partials [2][3][32768] -> ends 31047680
#define OFF_PCLU  31047680u   // clu partials [2][6][32768][8] = 3145728 -> ends 34193408
#define WS_NEED_FLOATS 37142528u
// after k_post2, pclu region is dead -> reuse for regions partials + fuse partials
#define OFF_RP3   OFF_PCLU                  // 2 x 1572864 -> ends 34193408
#define OFF_DP3   34193408u                 // 2 x 2048 -> ends 34197504
#define OFF_FP24  34197504u                 // 24*32*768 = 589824 -> ends 34787328

// ================== global_load_lds helper (16B, wave dest) ==================
__device__ __forceinline__ void gload16(const half_t* g, half_t* l)
{
    __builtin_amdgcn_global_load_lds(
        (const __attribute__((address_space(1))) void*)g,
        (__attribute__((address_space(3))) void*)l, 16, 0, 0);
}

// ============ f32 -> f16 feature conversion (both sets, one launch) ============
__global__ __launch_bounds__(256)
void k_cvt2(const float* __restrict__ sat, const float* __restrict__ uav,
            half_t* __restrict__ os, half_t* __restrict__ ou)
{
    const int set = blockIdx.x / 3072;
    const int b2 = blockIdx.x - set*3072;
    const float* in = set ? uav : sat;
    half_t* out = set ? ou : os;
    const int base = b2*256 + threadIdx.x;
#pragma unroll
    for (int i = 0; i < 8; i++) {
        const size_t idx4 = (size_t)i*786432 + base;
        const float4 v = *(const float4*)&in[idx4*4];
        half4 h;
        h[0] = (half_t)v.x; h[1] = (half_t)v.y; h[2] = (half_t)v.z; h[3] = (half_t)v.w;
        *(half4*)&out[idx4*4] = h;
    }
}

// ====== pack [imp_w1 | clu_w1] (K x N f32) -> Bp[n][k] f16 transposed ======
__global__ __launch_bounds__(256)
void k_packw(const float* __restrict__ wi1, const float* __restrict__ wc1,
             half_t* __restrict__ bp)
{
    const int id = blockIdx.x*256 + threadIdx.x;   // 221184
    if (id >= 221184) return;
    const int n = id / 192, k0 = (id % 192)*4;
    half4 h;
#pragma unroll
    for (int j = 0; j < 4; j++) {
        const float v = (n < 384) ? wi1[(size_t)(k0+j)*384 + n]
                                  : wc1[(size_t)(k0+j)*768 + (n - 384)];
        h[j] = (half_t)v;
    }
    *(half4*)&bp[(size_t)n*768 + k0] = h;
}

// ===== big GEMM + fused layer-2 partials. BK=32, swapped-operand epilogue. =====
// (byte-exact round-7/9 verified-deterministic version)
// logical grid: set(2) x mb(256) x nb(9) = 4608 blocks, XCD-swizzled.
// mfma(b, a) -> acc[mi][ni][q] = C[row0+mi*16+l15][ncol0+ni*16+g*4+q]
__global__ __launch_bounds__(256)
void k_gemm1p(const half_t* __restrict__ A0, const half_t* __restrict__ A1,
              const half_t* __restrict__ Bp,
              const float* __restrict__ b1i, const float* __restrict__ b1c,
              const float* __restrict__ w2i, const float* __restrict__ w2c,
              float* __restrict__ pimp, float* __restrict__ pclu)
{
    __shared__ half_t Als[128*32];
    __shared__ half_t Bls[128*32];
    __shared__ float redu[2048];          // 8 KB combine buffer
    const int t = threadIdx.x;
    const int lane = t & 63, wv = t >> 6;
    const int wm = wv >> 1, wn = wv & 1;
    const int l15 = lane & 15, g = lane >> 4;
    const int swz = (l15 >> 1) & 3;

    const int bid = blockIdx.x;
    const int xcd = bid & 7, kk = bid >> 3;
    const int mbh = kk / 9, nb = kk - mbh*9;
    const int mb = mbh*8 + xcd;            // 0..511
    const int set = mb >> 8;
    const int row0 = (mb & 255) * 128;
    const int n0 = nb * 128;
    const half_t* __restrict__ A = set ? A1 : A0;

    f32x4 acc[4][4];
#pragma unroll
    for (int mi = 0; mi < 4; mi++)
#pragma unroll
        for (int ni = 0; ni < 4; ni++)
#pragma unroll
            for (int q = 0; q < 4; q++) acc[mi][ni][q] = 0.f;

    size_t arow[2], brow[2];
#pragma unroll
    for (int i = 0; i < 2; i++) {
        const int u = (i*4 + wv)*64 + lane;
        const int maj = u >> 2;
        const int c = (u & 3) ^ ((maj >> 1) & 3);
        arow[i] = (size_t)(row0 + maj)*768 + c*8;
        brow[i] = (size_t)(n0  + maj)*768 + c*8;
    }

    for (int kt = 0; kt < 24; kt++) {
        const int ko = kt*32;
#pragma unroll
        for (int i = 0; i < 2; i++) {
            gload16(A  + arow[i] + ko, &Als[(i*4 + wv)*512]);
            gload16(Bp + brow[i] + ko, &Bls[(i*4 + wv)*512]);
        }
        __syncthreads();
        half8 a[4], b[4];
#pragma unroll
        for (int mi = 0; mi < 4; mi++) {
            const int maj = wm*64 + mi*16 + l15;
            a[mi] = *(const half8*)&Als[maj*32 + ((g ^ swz) << 3)];
        }
#pragma unroll
        for (int ni = 0; ni < 4; ni++) {
            const int maj = wn*64 + ni*16 + l15;
            b[ni] = *(const half8*)&Bls[maj*32 + ((g ^ swz) << 3)];
        }
        // swapped operand order: output fragment transposed
#pragma unroll
        for (int mi = 0; mi < 4; mi++)
#pragma unroll
            for (int ni = 0; ni < 4; ni++)
                acc[mi][ni] = __builtin_amdgcn_mfma_f32_16x16x32_f16(
                                  b[ni], a[mi], acc[mi][ni], 0, 0, 0);
        __syncthreads();
    }

    // ------- fused layer-2 partial epilogue (cheap reduction) -------
    if (nb < 3) {
        f32x4 b1q[4], w2q[4];
#pragma unroll
        for (int ni = 0; ni < 4; ni++) {
            const int c0 = n0 + wn*64 + ni*16 + g*4;
            b1q[ni] = *(const f32x4*)&b1i[c0];
            w2q[ni] = *(const f32x4*)&w2i[c0];
        }
        float pr[4];
#pragma unroll
        for (int mi = 0; mi < 4; mi++) {
            float s = 0.f;
#pragma unroll
            for (int ni = 0; ni < 4; ni++)
#pragma unroll
                for (int q = 0; q < 4; q++)
                    s += fmaxf(acc[mi][ni][q] + b1q[ni][q], 0.f) * w2q[ni][q];
            s += __shfl_xor(s, 16); s += __shfl_xor(s, 32);
            pr[mi] = s;
        }
        if (g == 0) {
#pragma unroll
            for (int mi = 0; mi < 4; mi++)
                redu[(wm*64 + mi*16 + l15)*2 + wn] = pr[mi];
        }
        __syncthreads();
        if (t < 128)
            pimp[(size_t)(set*3 + nb)*32768 + row0 + t] = redu[t*2] + redu[t*2+1];
    } else {
        const int nbc = nb - 3;
        const int colb = n0 - 384 + wn*64 + g*4;
        f32x4 lglo[4], lghi[4];
#pragma unroll
        for (int mi = 0; mi < 4; mi++) {
            lglo[mi] = (f32x4){0.f,0.f,0.f,0.f};
            lghi[mi] = (f32x4){0.f,0.f,0.f,0.f};
        }
#pragma unroll
        for (int ni = 0; ni < 4; ni++) {
            const int c0 = colb + ni*16;
            const f32x4 b1v = *(const f32x4*)&b1c[c0];
#pragma unroll
            for (int q = 0; q < 4; q++) {
                const f32x4 wlo = *(const f32x4*)&w2c[(c0+q)*8];
                const f32x4 whi = *(const f32x4*)&w2c[(c0+q)*8 + 4];
#pragma unroll
                for (int mi = 0; mi < 4; mi++) {
                    const float v = fmaxf(acc[mi][ni][q] + b1v[q], 0.f);
                    lglo[mi] += wlo * v;
                    lghi[mi] += whi * v;
                }
            }
        }
#pragma unroll
        for (int mi = 0; mi < 4; mi++)
#pragma unroll
            for (int e = 0; e < 4; e++) {
                float x = lglo[mi][e];
                x += __shfl_xor(x, 16); x += __shfl_xor(x, 32);
                lglo[mi][e] = x;
                float y = lghi[mi][e];
                y += __shfl_xor(y, 16); y += __shfl_xor(y, 32);
                lghi[mi][e] = y;
            }
        if (g == 0) {
#pragma unroll
            for (int mi = 0; mi < 4; mi++) {
                const int row = wm*64 + mi*16 + l15;
                *(f32x4*)&redu[(row*2 + wn)*8]     = lglo[mi];
                *(f32x4*)&redu[(row*2 + wn)*8 + 4] = lghi[mi];
            }
        }
        __syncthreads();
        {
            const int row = t >> 1, jh = (t & 1)*4;
            const f32x4 s0 = *(const f32x4*)&redu[(row*2 + 0)*8 + jh];
            const f32x4 s1 = *(const f32x4*)&redu[(row*2 + 1)*8 + jh];
            f32x4 s = s0 + s1;
            *(f32x4*)&pclu[((size_t)(set*6 + nbc)*32768 + row0 + row)*8 + jh] = s;
        }
    }
}

// ==== post2: reduce partials -> imp, softmax(clu logits), wi (both sets) ====
__global__ __launch_bounds__(256)
void k_post2(const float* __restrict__ pimp, const float* __restrict__ pclu,
             const float* __restrict__ b2i, const float* __restrict__ b2c,
             float* __restrict__ wi_s, float* __restrict__ wi_u)
{
    const int gid = blockIdx.x*256 + threadIdx.x;    // 65536
    const int set = gid >> 15, row = gid & 32767;
    const float* pi = pimp + (size_t)set*3*32768;
    const float* pc = pclu + (size_t)set*6*32768*8;
    const float imp = pi[row] + pi[32768 + row] + pi[2*32768 + row] + b2i[0];
    float lg[8];
#pragma unroll
    for (int j = 0; j < 8; j++) lg[j] = b2c[j];
#pragma unroll
    for (int c = 0; c < 6; c++) {
        const float4 a = *(const float4*)&pc[((size_t)c*32768 + row)*8];
        const float4 b = *(const float4*)&pc[((size_t)c*32768 + row)*8 + 4];
        lg[0] += a.x; lg[1] += a.y; lg[2] += a.z; lg[3] += a.w;
        lg[4] += b.x; lg[5] += b.y; lg[6] += b.z; lg[7] += b.w;
    }
    float mx = -1e30f;
#pragma unroll
    for (int j = 0; j < 8; j++) mx = fmaxf(mx, lg[j]);
    float sm = 0.f;
#pragma unroll
    for (int j = 0; j < 8; j++) { lg[j] = expf(lg[j] - mx); sm += lg[j]; }
    const float iv = imp / sm;
    float* wo = set ? wi_u : wi_s;
    float4 o0, o1;
    o0.x = lg[0]*iv; o0.y = lg[1]*iv; o0.z = lg[2]*iv; o0.w = lg[3]*iv;
    o1.x = lg[4]*iv; o1.y = lg[5]*iv; o1.z = lg[6]*iv; o1.w = lg[7]*iv;
    *(float4*)&wo[(size_t)row*8]     = o0;
    *(float4*)&wo[(size_t)row*8 + 4] = o1;
}

// ======= regions phase A (f16 features, 8 s-segments, both sets) =======
__global__ __launch_bounds__(192)
void k_regions_a3(const half_t* __restrict__ fs, const half_t* __restrict__ fu,
                  const float* __restrict__ wis, const float* __restrict__ wiu,
                  float* __restrict__ partb, float* __restrict__ dpartb)
{
    __shared__ float wil[128*8];
    const int t = threadIdx.x;
    const int sseg = blockIdx.x, b = blockIdx.y, zz = blockIdx.z;
    const half_t* f = zz ? fu : fs;
    const float* wi = zz ? wiu : wis;
    float* part  = partb  + (size_t)zz*1572864u;
    float* dpart = dpartb + (size_t)zz*2048u;
    const int s0 = sseg*128;
    for (int l = t; l < 256; l += 192)
        *(float4*)&wil[l*4] = *(const float4*)&wi[((size_t)b*SS + s0)*8 + l*4];
    __syncthreads();
    if (t < 8) {
        float p = 0.f;
        for (int s = 0; s < 128; s++) p += wil[s*8 + t];
        dpart[((size_t)sseg*32 + b)*8 + t] = p;
    }
    f32x4 acc[8];
#pragma unroll
    for (int r = 0; r < 8; r++) acc[r] = (f32x4){0.f,0.f,0.f,0.f};
    const half_t* fp = f + ((size_t)b*SS + s0)*768 + t*4;
#pragma unroll 4
    for (int s = 0; s < 128; s++) {
        const half4 hv = *(const half4*)&fp[(size_t)s*768];
        f32x4 vv;
        vv[0] = (float)hv[0]; vv[1] = (float)hv[1];
        vv[2] = (float)hv[2]; vv[3] = (float)hv[3];
#pragma unroll
        for (int r = 0; r < 8; r++) acc[r] += vv * wil[s*8 + r];
    }
#pragma unroll
    for (int r = 0; r < 8; r++) {
        float4 o; o.x = acc[r][0]; o.y = acc[r][1]; o.z = acc[r][2]; o.w = acc[r][3];
        *(float4*)&part[(((size_t)sseg*8 + r)*32 + b)*768 + t*4] = o;
    }
}

// ====== regions phase B: reg = sum_sseg part / (den+1e-8), both sets ======
__global__ __launch_bounds__(256)
void k_regions_b3(const float* __restrict__ partb, const float* __restrict__ dpartb,
                  float* __restrict__ reg_s, float* __restrict__ reg_u)
{
    __shared__ float dinv_s;
    const int t = threadIdx.x;
    const int zz = blockIdx.y;
    const float* part  = partb  + (size_t)zz*1572864u;
    const float* dpart = dpartb + (size_t)zz*2048u;
    float* reg = zz ? reg_u : reg_s;
    const int r = blockIdx.x >> 5, b = blockIdx.x & 31;
    if (t == 0) {
        float s = 0.f;
        for (int q = 0; q < 8; q++) s += dpart[((size_t)q*32 + b)*8 + r];
        dinv_s = 1.f / (s + 1e-8f);
    }
    __syncthreads();
    const float dinv = dinv_s;
#pragma unroll
    for (int i = 0; i < 3; i++) {
        const int d = t + i*256;
        float s = 0.f;
#pragma unroll
        for (int q = 0; q < 8; q++)
            s += part[(((size_t)q*8 + r)*32 + b)*768 + d];
        reg[((size_t)r*BB + b)*DD + d] = s * dinv;
    }
}

// ====== fp32 GEMM small-M: C = act(A@W + bscale*bias), 32x32 tile ======
__global__ __launch_bounds__(256)
void gemm32(const float* __restrict__ A, int lda,
            const float* __restrict__ W, int ldw,
            const float* __restrict__ bias, float bscale, int do_relu,
            float* __restrict__ C, int ldc, int K)
{
    __shared__ float As[32*36];
    __shared__ float Bs[32*36];
    const int t = threadIdx.x;
    const int row0 = blockIdx.x*32, n0 = blockIdx.y*32;
    const int lr = t >> 3, lc4 = (t & 7)*4;
    float4 acc = make_float4(0.f,0.f,0.f,0.f);
    for (int kt = 0; kt < K; kt += 32) {
        *(float4*)&As[lr*36 + lc4] = *(const float4*)&A[(size_t)(row0+lr)*lda + kt + lc4];
        *(float4*)&Bs[lr*36 + lc4] = *(const float4*)&W[(size_t)(kt+lr)*ldw + n0 + lc4];
        __syncthreads();
#pragma unroll
        for (int k = 0; k < 32; k++) {
            const float a = As[lr*36 + k];
            const float4 b4 = *(const float4*)&Bs[k*36 + lc4];
            acc.x += a*b4.x; acc.y += a*b4.y; acc.z += a*b4.z; acc.w += a*b4.w;
        }
        __syncthreads();
    }
    float4 o = acc;
    if (bias) {
        const float4 b4 = *(const float4*)&bias[n0 + lc4];
        o.x += b4.x*bscale; o.y += b4.y*bscale; o.z += b4.z*bscale; o.w += b4.w*bscale;
    }
    if (do_relu) {
        o.x = fmaxf(o.x,0.f); o.y = fmaxf(o.y,0.f);
        o.z = fmaxf(o.z,0.f); o.w = fmaxf(o.w,0.f);
    }
    *(float4*)&C[(size_t)(row0+lr)*ldc + n0 + lc4] = o;
}

// ====== Ai/Bj batched: z=0: C0 = A0@W + b ; z=1: C1 = A1@(W+768*768) ======
__global__ __launch_bounds__(256)
void gemm32z(const float* __restrict__ A0, const float* __restrict__ A1,
             const float* __restrict__ W, const float* __restrict__ bias,
             float* __restrict__ C0, float* __restrict__ C1)
{
    __shared__ float As[32*36];
    __shared__ float Bs[32*36];
    const int t = threadIdx.x;
    const int zz = blockIdx.z;
    const float* A = zz ? A1 : A0;
    const float* Wp = W + (size_t)zz*768*768;
    float* C = zz ? C1 : C0;
    const int row0 = blockIdx.x*32, n0 = blockIdx.y*32;
    const int lr = t >> 3, lc4 = (t & 7)*4;
    float4 acc = make_float4(0.f,0.f,0.f,0.f);
    for (int kt = 0; kt < 768; kt += 32) {
        *(float4*)&As[lr*36 + lc4] = *(const float4*)&A[(size_t)(row0+lr)*768 + kt + lc4];
        *(float4*)&Bs[lr*36 + lc4] = *(const float4*)&Wp[(size_t)(kt+lr)*768 + n0 + lc4];
        __syncthreads();
#pragma unroll
        for (int k = 0; k < 32; k++) {
            const float a = As[lr*36 + k];
            const float4 b4 = *(const float4*)&Bs[k*36 + lc4];
            acc.x += a*b4.x; acc.y += a*b4.y; acc.z += a*b4.z; acc.w += a*b4.w;
        }
        __syncthreads();
    }
    float4 o = acc;
    if (zz == 0) {
        const float4 b4 = *(const float4*)&bias[n0 + lc4];
        o.x += b4.x; o.y += b4.y; o.z += b4.z; o.w += b4.w;
    }
    *(float4*)&C[(size_t)(row0+lr)*768 + n0 + lc4] = o;
}

// ====== h2 fused: h2 = relu( relu(Ai[i]+Bj[j]) @ sim_w2 + b2 ), h1 on the fly ======
// grid (64 ij, 12 nb); rows = ij*32 + b
__global__ __launch_bounds__(256)
void k_h2f(const float* __restrict__ Ai, const float* __restrict__ Bj,
           const float* __restrict__ W, const float* __restrict__ bias,
           float* __restrict__ C)
{
    __shared__ float As[32*36];
    __shared__ float Bs[32*36];
    const int t = threadIdx.x;
    const int ij = blockIdx.x, n0 = blockIdx.y*32;
    const int i = ij >> 3, j = ij & 7;
    const int lr = t >> 3, lc4 = (t & 7)*4;
    float4 acc = make_float4(0.f,0.f,0.f,0.f);
    for (int kt = 0; kt < 768; kt += 32) {
        const float4 a4 = *(const float4*)&Ai[(size_t)(i*32+lr)*768 + kt + lc4];
        const float4 b4 = *(const float4*)&Bj[(size_t)(j*32+lr)*768 + kt + lc4];
        float4 h1v;
        h1v.x = fmaxf(a4.x + b4.x, 0.f); h1v.y = fmaxf(a4.y + b4.y, 0.f);
        h1v.z = fmaxf(a4.z + b4.z, 0.f); h1v.w = fmaxf(a4.w + b4.w, 0.f);
        *(float4*)&As[lr*36 + lc4] = h1v;
        *(float4*)&Bs[lr*36 + lc4] = *(const float4*)&W[(size_t)(kt+lr)*384 + n0 + lc4];
        __syncthreads();
#pragma unroll
        for (int k = 0; k < 32; k++) {
            const float a = As[lr*36 + k];
            const float4 w4 = *(const float4*)&Bs[k*36 + lc4];
            acc.x += a*w4.x; acc.y += a*w4.y; acc.z += a*w4.z; acc.w += a*w4.w;
        }
        __syncthreads();
    }
    const float4 bb = *(const float4*)&bias[n0 + lc4];
    float4 o;
    o.x = fmaxf(acc.x + bb.x, 0.f); o.y = fmaxf(acc.y + bb.y, 0.f);
    o.z = fmaxf(acc.z + bb.z, 0.f); o.w = fmaxf(acc.w + bb.w, 0.f);
    *(float4*)&C[(size_t)(ij*32+lr)*384 + n0 + lc4] = o;
}

// ====== attn-V fused: t1 = (rs[r]+ru[idx[r]]) @ attn_wv + 2*bv ======
// grid (8 r, 24 nb)
__global__ __launch_bounds__(256)
void k_zwv(const float* __restrict__ rs, const float* __restrict__ ru,
           const int* __restrict__ idx, const float* __restrict__ W,
           const float* __restrict__ bias, float* __restrict__ C)
{
    __shared__ float As[32*36];
    __shared__ float Bs[32*36];
    const int t = threadIdx.x;
    const int r = blockIdx.x, n0 = blockIdx.y*32;
    const int ir = idx[r];
    const int lr = t >> 3, lc4 = (t & 7)*4;
    float4 acc = make_float4(0.f,0.f,0.f,0.f);
    for (int kt = 0; kt < 768; kt += 32) {
        const float4 a4 = *(const float4*)&rs[(size_t)(r*32+lr)*768 + kt + lc4];
        const float4 b4 = *(const float4*)&ru[(size_t)(ir*32+lr)*768 + kt + lc4];
        float4 z4;
        z4.x = a4.x + b4.x; z4.y = a4.y + b4.y;
        z4.z = a4.z + b4.z; z4.w = a4.w + b4.w;
        *(float4*)&As[lr*36 + lc4] = z4;
        *(float4*)&Bs[lr*36 + lc4] = *(const float4*)&W[(size_t)(kt+lr)*768 + n0 + lc4];
        __syncthreads();
#pragma unroll
        for (int k = 0; k < 32; k++) {
            const float a = As[lr*36 + k];
            const float4 w4 = *(const float4*)&Bs[k*36 + lc4];
            acc.x += a*w4.x; acc.y += a*w4.y; acc.z += a*w4.z; acc.w += a*w4.w;
        }
        __syncthreads();
    }
    const float4 bb = *(const float4*)&bias[n0 + lc4];
    float4 o;
    o.x = acc.x + 2.f*bb.x; o.y = acc.y + 2.f*bb.y;
    o.z = acc.z + 2.f*bb.z; o.w = acc.w + 2.f*bb.w;
    *(float4*)&C[(size_t)(r*32+lr)*768 + n0 + lc4] = o;
}

// =================== FALLBACK path (round-2 kernels) ===================
__global__ __launch_bounds__(256)
void k_pack(const float* __restrict__ wsrc, half_t* __restrict__ p, int KT, int NT)
{
    const int u = blockIdx.x*256 + threadIdx.x;
    const int per_kt = NT*64;
    if (u >= KT*per_kt) return;
    const int kt = u / per_kt, rem = u % per_kt;
    const int nt = rem >> 6, lane = rem & 63;
    const int N = NT*16;
    const int k0 = kt*16 + ((lane>>4)<<2), n = nt*16 + (lane & 15);
    half4 hq;
#pragma unroll
    for (int j = 0; j < 4; j++) hq[j] = (half_t)wsrc[(size_t)(k0+j)*N + n];
    *(half4*)&p[(size_t)u*4] = hq;
}

__global__ __launch_bounds__(256)
void k_imp_mfma(const float* __restrict__ f, const half_t* __restrict__ wp,
                const float* __restrict__ b1, const float* __restrict__ w2,
                const float* __restrict__ b2, float* __restrict__ imp_out)
{
    __shared__ half_t Wb[24*64*4];
    __shared__ half_t Ab[2*64*4];
    __shared__ float red[4][32];
    const int t = threadIdx.x;
    const int w = t >> 6, lane = t & 63;
    const int row0 = blockIdx.x * 32;
    const float4* wp4 = (const float4*)wp;
    f32x4 acc[2][6];
#pragma unroll
    for (int m = 0; m < 2; m++)
#pragma unroll
        for (int i = 0; i < 6; i++)
#pragma unroll
            for (int q = 0; q < 4; q++) acc[m][i][q] = 0.f;
    const int arow = t >> 2, akg = t & 3;
    const float* fA = f + (size_t)(row0 + arow)*768;
    float4 wreg[3]; float4 areg;
#pragma unroll
    for (int i = 0; i < 3; i++) wreg[i] = wp4[i*256 + t];
    if (t < 128) areg = *(const float4*)&fA[akg*4];
    for (int kt = 0; kt < 48; kt++) {
#pragma unroll
        for (int i = 0; i < 3; i++) *(float4*)&Wb[(i*256 + t)*8] = wreg[i];
        if (t < 128) {
            half4 ah;
            ah[0] = (half_t)areg.x; ah[1] = (half_t)areg.y;
            ah[2] = (half_t)areg.z; ah[3] = (half_t)areg.w;
            *(half4*)&Ab[(((arow>>4)<<6) + (akg<<4) + (arow & 15))*4] = ah;
        }
        __syncthreads();
        if (kt < 47) {
#pragma unroll
            for (int i = 0; i < 3; i++) wreg[i] = wp4[(kt+1)*768 + i*256 + t];
            if (t < 128) areg = *(const float4*)&fA[(kt+1)*16 + akg*4];
        }
        half4 a0 = *(half4*)&Ab[lane*4];
        half4 a1 = *(half4*)&Ab[(64 + lane)*4];
#pragma unroll
        for (int i = 0; i < 6; i++) {
            half4 bf = *(half4*)&Wb[((w*6 + i)*64 + lane)*4];
            acc[0][i] = __builtin_amdgcn_mfma_f32_16x16x16f16(a0, bf, acc[0][i], 0, 0, 0);
            acc[1][i] = __builtin_amdgcn_mfma_f32_16x16x16f16(a1, bf, acc[1][i], 0, 0, 0);
        }
        __syncthreads();
    }
    float b1v[6], w2v[6];
#pragma unroll
    for (int i = 0; i < 6; i++) {
        const int col = (w*6 + i)*16 + (lane & 15);
        b1v[i] = b1[col]; w2v[i] = w2[col];
    }
#pragma unroll
    for (int m = 0; m < 2; m++)
#pragma unroll
        for (int r = 0; r < 4; r++) {
            float s = 0.f;
#pragma unroll
            for (int i = 0; i < 6; i++)
                s += fmaxf(acc[m][i][r] + b1v[i], 0.f) * w2v[i];
            s += __shfl_xor(s,1); s += __shfl_xor(s,2);
            s += __shfl_xor(s,4); s += __shfl_xor(s,8);
            if ((lane & 15) == 0) red[w][m*16 + ((lane>>4)<<2) + r] = s;
        }
    __syncthreads();
    if (t < 32)
        imp_out[row0 + t] = red[0][t] + red[1][t] + red[2][t] + red[3][t] + b2[0];
}

__global__ __launch_bounds__(256)
void k_clu_mfma(const float* __restrict__ f, const half_t* __restrict__ wp,
                const float* __restrict__ b1, const float* __restrict__ w2,
                const float* __restrict__ b2, const float* __restrict__ imp,
                float* __restrict__ wi_out)
{
    __shared__ half_t Wb[48*64*4];
    __shared__ half_t Ab[2*64*4];
    __shared__ float red[4][32][8];
    const int t = threadIdx.x;
    const int w = t >> 6, lane = t & 63;
    const int row0 = blockIdx.x * 32;
    const float4* wp4 = (const float4*)wp;
    f32x4 acc[2][12];
#pragma unroll
    for (int m = 0; m < 2; m++)
#pragma unroll
        for (int i = 0; i < 12; i++)
#pragma unroll
            for (int q = 0; q < 4; q++) acc[m][i][q] = 0.f;
    const int arow = t >> 2, akg = t & 3;
    const float* fA = f + (size_t)(row0 + arow)*768;
    float4 wreg[6]; float4 areg;
#pragma unroll
    for (int i = 0; i < 6; i++) wreg[i] = wp4[i*256 + t];
    if (t < 128) areg = *(const float4*)&fA[akg*4];
    for (int kt = 0; kt < 48; kt++) {
#pragma unroll
        for (int i = 0; i < 6; i++) *(float4*)&Wb[(i*256 + t)*8] = wreg[i];
        if (t < 128) {
            half4 ah;
            ah[0] = (half_t)areg.x; ah[1] = (half_t)areg.y;
            ah[2] = (half_t)areg.z; ah[3] = (half_t)areg.w;
            *(half4*)&Ab[(((arow>>4)<<6) + (akg<<4) + (arow & 15))*4] = ah;
        }
        __syncthreads();
        if (kt < 47) {
#pragma unroll
            for (int i = 0; i < 6; i++) wreg[i] = wp4[(kt+1)*1536 + i*256 + t];
            if (t < 128) areg = *(const float4*)&fA[(kt+1)*16 + akg*4];
        }
        half4 a0 = *(half4*)&Ab[lane*4];
        half4 a1 = *(half4*)&Ab[(64 + lane)*4];
#pragma unroll
        for (int i = 0; i < 12; i++) {
            half4 bf = *(half4*)&Wb[((w*12 + i)*64 + lane)*4];
            acc[0][i] = __builtin_amdgcn_mfma_f32_16x16x16f16(a0, bf, acc[0][i], 0, 0, 0);
            acc[1][i] = __builtin_amdgcn_mfma_f32_16x16x16f16(a1, bf, acc[1][i], 0, 0, 0);
        }
        __syncthreads();
    }
    float b1v[12];
#pragma unroll
    for (int i = 0; i < 12; i++) b1v[i] = b1[(w*12 + i)*16 + (lane & 15)];
#pragma unroll
    for (int h = 0; h < 2; h++) {
        float lg[2][4][4];
#pragma unroll
        for (int m = 0; m < 2; m++)
#pragma unroll
            for (int r = 0; r < 4; r++)
#pragma unroll
                for (int q = 0; q < 4; q++) lg[m][r][q] = 0.f;
#pragma unroll
        for (int i = 0; i < 12; i++) {
            const int col = (w*12 + i)*16 + (lane & 15);
            const float4 w2v = *(const float4*)&w2[col*8 + h*4];
#pragma unroll
            for (int m = 0; m < 2; m++)
#pragma unroll
                for (int r = 0; r < 4; r++) {
                    const float v = fmaxf(acc[m][i][r] + b1v[i], 0.f);
                    lg[m][r][0] += v*w2v.x; lg[m][r][1] += v*w2v.y;
                    lg[m][r][2] += v*w2v.z; lg[m][r][3] += v*w2v.w;
                }
        }
#pragma unroll
        for (int m = 0; m < 2; m++)
#pragma unroll
            for (int r = 0; r < 4; r++)
#pragma unroll
                for (int q = 0; q < 4; q++) {
                    float s = lg[m][r][q];
                    s += __shfl_xor(s,1); s += __shfl_xor(s,2);
                    s += __shfl_xor(s,4); s += __shfl_xor(s,8);
                    if ((lane & 15) == 0)
                        red[w][m*16 + ((lane>>4)<<2) + r][h*4 + q] = s;
                }
    }
    __syncthreads();
    if (t < 32) {
        float l8[8], mx = -1e30f;
#pragma unroll
        for (int r8 = 0; r8 < 8; r8++) {
            l8[r8] = red[0][t][r8] + red[1][t][r8] + red[2][t][r8] + red[3][t][r8] + b2[r8];
            mx = fmaxf(mx, l8[r8]);
        }
        float s = 0.f;
#pragma unroll
        for (int r8 = 0; r8 < 8; r8++) { l8[r8] = expf(l8[r8] - mx); s += l8[r8]; }
        const float iv = imp[row0 + t] / s;
#pragma unroll
        for (int r8 = 0; r8 < 8; r8++) wi_out[(row0 + t)*8 + r8] = l8[r8] * iv;
    }
}

__global__ __launch_bounds__(256)
void k_regions(const float* __restrict__ f, const float* __restrict__ wi,
               float* __restrict__ reg)
{
    __shared__ float wil[SS*8];
    __shared__ float pden[64];
    __shared__ float dinv[8];
    __shared__ float pacc[256*8];
    const int t = threadIdx.x, b = blockIdx.x, dc = blockIdx.y;
    for (int l = t; l < SS*8; l += 256) wil[l] = wi[(size_t)b*SS*8 + l];
    __syncthreads();
    if (t < 64) {
        const int r = t & 7, seg = t >> 3;
        float p = 0.f;
        for (int s = seg*128; s < seg*128 + 128; s++) p += wil[s*8 + r];
        pden[t] = p;
    }
    __syncthreads();
    if (t < 8) {
        float dsum = 0.f;
        for (int g = 0; g < 8; g++) dsum += pden[g*8 + t];
        dinv[t] = 1.f / (dsum + 1e-8f);
    }
    const int dl = t & 63, sseg = t >> 6;
    const int d = dc*64 + dl;
    float acc[8] = {0,0,0,0,0,0,0,0};
    const float* fp = f + (size_t)b*SS*DD + d;
    for (int s = sseg*256; s < (sseg+1)*256; s++) {
        const float v = fp[(size_t)s*DD];
        const float4 w0 = *(const float4*)&wil[s*8];
        const float4 w1 = *(const float4*)&wil[s*8 + 4];
        acc[0] += v*w0.x; acc[1] += v*w0.y; acc[2] += v*w0.z; acc[3] += v*w0.w;
        acc[4] += v*w1.x; acc[5] += v*w1.y; acc[6] += v*w1.z; acc[7] += v*w1.w;
    }
#pragma unroll
    for (int r = 0; r < 8; r++) pacc[t*8 + r] = acc[r];
    __syncthreads();
    if (t < 64) {
#pragma unroll
        for (int r = 0; r < 8; r++) {
            const float s = pacc[(0*64+t)*8+r] + pacc[(1*64+t)*8+r]
                          + pacc[(2*64+t)*8+r] + pacc[(3*64+t)*8+r];
            reg[((size_t)r*BB + b)*DD + dc*64 + t] = s * dinv[r];
        }
    }
}

// ========== sim[i,j] = mean_b sigmoid(h2[i,j,b,:] @ w3 + b3) ==========
__global__ __launch_bounds__(256)
void k_sim(const float* __restrict__ h2, const float* __restrict__ w3,
           const float* __restrict__ b3, float* __restrict__ sim)
{
    __shared__ float sv[32];
    const int t = threadIdx.x, ij = blockIdx.x;
    const int b = t >> 3, g = t & 7;
    const float* row = h2 + (size_t)(ij*32 + b)*384;
    float p = 0.f;
    for (int c = g*48; c < g*48 + 48; c++) p += row[c]*w3[c];
    p += __shfl_xor(p,1); p += __shfl_xor(p,2); p += __shfl_xor(p,4);
    if (g == 0) sv[b] = 1.f/(1.f + expf(-(p + b3[0])));
    __syncthreads();
    if (t == 0) {
        float m = 0.f;
        for (int i = 0; i < 32; i++) m += sv[i];
        sim[ij] = m / 32.f;
    }
}

__global__ void k_match(const float* __restrict__ sim, int* __restrict__ idx)
{
    if (threadIdx.x == 0) {
        bool used[8] = {false,false,false,false,false,false,false,false};
        for (int i = 0; i < 8; i++) {
            float m = -2.f; int jj = 0;
            for (int j = 0; j < 8; j++) {
                const float s = used[j] ? -1.f : sim[i*8 + j];
                if (s > m) { m = s; jj = j; }
            }
            idx[i] = jj; used[jj] = true;
        }
    }
}

__device__ __forceinline__ float block_sum_256(float v, float* red)
{
#pragma unroll
    for (int m = 1; m < 64; m <<= 1) v += __shfl_xor(v, m);
    const int t = threadIdx.x;
    __syncthreads();
    if ((t & 63) == 0) red[t >> 6] = v;
    __syncthreads();
    return red[0] + red[1] + red[2] + red[3];
}

__global__ __launch_bounds__(256)
void k_ln(const float* __restrict__ x, const float* __restrict__ g,
          const float* __restrict__ bta, float* __restrict__ y)
{
    __shared__ float red[4];
    const int row = blockIdx.x, t = threadIdx.x;
    float v[3];
#pragma unroll
    for (int i = 0; i < 3; i++) v[i] = x[(size_t)row*768 + t + i*256];
    float s = v[0] + v[1] + v[2];
    s = block_sum_256(s, red);
    const float m = s / 768.f;
    float q = 0.f;
#pragma unroll
    for (int i = 0; i < 3; i++) { const float d = v[i]-m; q += d*d; }
    q = block_sum_256(q, red);
    const float inv = rsqrtf(q/768.f + 1e-5f);
#pragma unroll
    for (int i = 0; i < 3; i++) {
        const int c = t + i*256;
        y[(size_t)row*768 + c] = (v[i]-m)*inv*g[c] + bta[c];
    }
}

// ============== fuse GEMM split-K 8 (fallback) =========
__global__ __launch_bounds__(256)
void k_fuse_gemm(const float* __restrict__ pool, const float* __restrict__ fw,
                 float* __restrict__ part)
{
    __shared__ float As[32*20];
    __shared__ float Ws[16*64];
    const int t = threadIdx.x;
    const int cg = t & 15, rg = t >> 4;
    const int kc = blockIdx.x, nb = blockIdx.y;
    float acc[2][4];
#pragma unroll
    for (int r = 0; r < 2; r++)
#pragma unroll
        for (int j = 0; j < 4; j++) acc[r][j] = 0.f;
    for (int kt = 0; kt < 768; kt += 16) {
        if (t < 128) {
            const int k4 = (t & 3)*4, r = t >> 2;
            *(float4*)&As[r*20 + k4] = *(const float4*)&pool[(size_t)(kc*32 + r)*768 + kt + k4];
        }
        {
            const int nq = (t & 15)*4, k = t >> 4;
            *(float4*)&Ws[k*64 + nq] = *(const float4*)&fw[(size_t)(kc*768 + kt + k)*768 + nb*64 + nq];
        }
        __syncthreads();
#pragma unroll
        for (int k = 0; k < 16; k++) {
            const float4 w = *(const float4*)&Ws[k*64 + cg*4];
            const float a0 = As[(rg*2+0)*20+k], a1 = As[(rg*2+1)*20+k];
            acc[0][0]+=a0*w.x; acc[0][1]+=a0*w.y; acc[0][2]+=a0*w.z; acc[0][3]+=a0*w.w;
            acc[1][0]+=a1*w.x; acc[1][1]+=a1*w.y; acc[1][2]+=a1*w.z; acc[1][3]+=a1*w.w;
        }
        __syncthreads();
    }
#pragma unroll
    for (int r = 0; r < 2; r++) {
        float4 o; o.x = acc[r][0]; o.y = acc[r][1]; o.z = acc[r][2]; o.w = acc[r][3];
        *(float4*)&part[(size_t)(kc*32 + rg*2 + r)*768 + nb*64 + cg*4] = o;
    }
}

__global__ __launch_bounds__(256)
void k_fuse_final(const float* __restrict__ part, const float* __restrict__ fb,
                  const float* __restrict__ g, const float* __restrict__ bta,
                  float* __restrict__ out)
{
    __shared__ float red[4];
    const int b = blockIdx.x, t = threadIdx.x;
    float v[3];
#pragma unroll
    for (int i = 0; i < 3; i++) {
        const int c = t + i*256;
        float s = 0.f;
#pragma unroll
        for (int kc = 0; kc < 8; kc++) s += part[(size_t)(kc*32 + b)*768 + c];
        v[i] = s + fb[c];
    }
    float s = v[0] + v[1] + v[2];
    s = block_sum_256(s, red);
    const float m = s / 768.f;
    float q = 0.f;
#pragma unroll
    for (int i = 0; i < 3; i++) { const float d = v[i]-m; q += d*d; }
    q = block_sum_256(q, red);
    const float inv = rsqrtf(q/768.f + 1e-5f);
#pragma unroll
    for (int i = 0; i < 3; i++) {
        const int c = t + i*256;
        out[(size_t)b*768 + c] = fmaxf((v[i]-m)*inv*g[c] + bta[c], 0.f);
    }
}

// ============== fuse GEMM split-K 24 (big path) =========
__global__ __launch_bounds__(256)
void k_fuse_gemm24(const float* __restrict__ pool, const float* __restrict__ fw,
                   float* __restrict__ part)
{
    __shared__ float As[32*20];
    __shared__ float Ws[16*64];
    const int t = threadIdx.x;
    const int cg = t & 15, rg = t >> 4;
    const int kc = blockIdx.x, nb = blockIdx.y;
    const int rr = kc / 3, d0 = (kc % 3) * 256;
    float acc[2][4];
#pragma unroll
    for (int r = 0; r < 2; r++)
#pragma unroll
        for (int j = 0; j < 4; j++) acc[r][j] = 0.f;
    for (int kt = 0; kt < 256; kt += 16) {
        if (t < 128) {
            const int k4 = (t & 3)*4, r = t >> 2;
            *(float4*)&As[r*20 + k4] = *(const float4*)&pool[(size_t)(rr*32 + r)*768 + d0 + kt + k4];
        }
        {
            const int nq = (t & 15)*4, k = t >> 4;
            *(float4*)&Ws[k*64 + nq] = *(const float4*)&fw[(size_t)(rr*768 + d0 + kt + k)*768 + nb*64 + nq];
        }
        __syncthreads();
#pragma unroll
        for (int k = 0; k < 16; k++) {
            const float4 w = *(const float4*)&Ws[k*64 + cg*4];
            const float a0 = As[(rg*2+0)*20+k], a1 = As[(rg*2+1)*20+k];
            acc[0][0]+=a0*w.x; acc[0][1]+=a0*w.y; acc[0][2]+=a0*w.z; acc[0][3]+=a0*w.w;
            acc[1][0]+=a1*w.x; acc[1][1]+=a1*w.y; acc[1][2]+=a1*w.z; acc[1][3]+=a1*w.w;
        }
        __syncthreads();
    }
#pragma unroll
    for (int r = 0; r < 2; r++) {
        float4 o; o.x = acc[r][0]; o.y = acc[r][1]; o.z = acc[r][2]; o.w = acc[r][3];
        *(float4*)&part[(size_t)(kc*32 + rg*2 + r)*768 + nb*64 + cg*4] = o;
    }
}

__global__ __launch_bounds__(256)
void k_fuse_final24(const float* __restrict__ part, const float* __restrict__ fb,
                    const float* __restrict__ g, const float* __restrict__ bta,
                    float* __restrict__ out)
{
    __shared__ float red[4];
    const int b = blockIdx.x, t = threadIdx.x;
    float v[3];
#pragma unroll
    for (int i = 0; i < 3; i++) {
        const int c = t + i*256;
        float s = 0.f;
#pragma unroll
        for (int kc = 0; kc < 24; kc++) s += part[(size_t)(kc*32 + b)*768 + c];
        v[i] = s + fb[c];
    }
    float s = v[0] + v[1] + v[2];
    s = block_sum_256(s, red);
    const float m = s / 768.f;
    float q = 0.f;
#pragma unroll
    for (int i = 0; i < 3; i++) { const float d = v[i]-m; q += d*d; }
    q = block_sum_256(q, red);
    const float inv = rsqrtf(q/768.f + 1e-5f);
#pragma unroll
    for (int i = 0; i < 3; i++) {
        const int c = t + i*256;
        out[(size_t)b*768 + c] = fmaxf((v[i]-m)*inv*g[c] + bta[c], 0.f);
    }
}

// ============================== launcher ==============================
extern "C" void kernel_launch(void* const* d_in, const int* in_sizes, int n_in,
                              void* d_out, int out_size, void* d_ws, size_t ws_size,
                              hipStream_t stream)
{
    (void)in_sizes; (void)n_in; (void)out_size;
    const float* sat     = (const float*)d_in[0];
    const float* uav     = (const float*)d_in[1];
    const float* imp_w1  = (const float*)d_in[2];
    const float* imp_b1  = (const float*)d_in[3];
    const float* imp_w2  = (const float*)d_in[4];
    const float* imp_b2  = (const float*)d_in[5];
    const float* clu_w1  = (const float*)d_in[6];
    const float* clu_b1  = (const float*)d_in[7];
    const float* clu_w2  = (const float*)d_in[8];
    const float* clu_b2  = (const float*)d_in[9];
    const float* sim_w1  = (const float*)d_in[10];
    const float* sim_b1  = (const float*)d_in[11];
    const float* sim_w2  = (const float*)d_in[12];
    const float* sim_b2  = (const float*)d_in[13];
    const float* sim_w3  = (const float*)d_in[14];
    const float* sim_b3  = (const float*)d_in[15];
    const float* attn_wv = (const float*)d_in[16];
    const float* attn_bv = (const float*)d_in[17];
    const float* attn_wo = (const float*)d_in[18];
    const float* attn_bo = (const float*)d_in[19];
    const float* pool_g  = (const float*)d_in[20];
    const float* pool_b  = (const float*)d_in[21];
    const float* fuse_w  = (const float*)d_in[22];
    const float* fuse_b  = (const float*)d_in[23];
    const float* fuse_g  = (const float*)d_in[24];
    const float* fuse_bt = (const float*)d_in[25];
    float* ws  = (float*)d_ws;
    float* out = (float*)d_out;

    const bool big = (ws_size >= (size_t)WS_NEED_FLOATS * 4u);
    if (big) {
        half_t* a16s = (half_t*)(ws + OFF_A16S);
        half_t* a16u = (half_t*)(ws + OFF_A16U);
        half_t* bp   = (half_t*)(ws + OFF_BP);

        k_packw<<<864, 256, 0, stream>>>(imp_w1, clu_w1, bp);
        k_cvt2<<<6144, 256, 0, stream>>>(sat, uav, a16s, a16u);
        k_gemm1p<<<4608, 256, 0, stream>>>(a16s, a16u, bp, imp_b1, clu_b1,
                                           imp_w2, clu_w2,
                                           ws + OFF_PIMP, ws + OFF_PCLU);
        k_post2<<<256, 256, 0, stream>>>(ws + OFF_PIMP, ws + OFF_PCLU,
                                         imp_b2, clu_b2,
                                         ws + OFF_WI_S, ws + OFF_WI_U);
        k_regions_a3<<<dim3(8,32,2), 192, 0, stream>>>(a16s, a16u,
                                                       ws + OFF_WI_S, ws + OFF_WI_U,
                                                       ws + OFF_RP3, ws + OFF_DP3);
        k_regions_b3<<<dim3(256,2), 256, 0, stream>>>(ws + OFF_RP3, ws + OFF_DP3,
                                                      ws + OFF_REG_S, ws + OFF_REG_U);
    } else {
        half_t* wpi = (half_t*)(ws + OFF_WPI);
        half_t* wpc = (half_t*)(ws + OFF_WPC);
        k_pack<<<288, 256, 0, stream>>>(imp_w1, wpi, 48, 24);
        k_pack<<<576, 256, 0, stream>>>(clu_w1, wpc, 48, 48);
        k_imp_mfma<<<1024, 256, 0, stream>>>(sat, wpi, imp_b1, imp_w2, imp_b2, ws + OFF_IMP_S);
        k_imp_mfma<<<1024, 256, 0, stream>>>(uav, wpi, imp_b1, imp_w2, imp_b2, ws + OFF_IMP_U);
        k_clu_mfma<<<1024, 256, 0, stream>>>(sat, wpc, clu_b1, clu_w2, clu_b2, ws + OFF_IMP_S, ws + OFF_WI_S);
        k_clu_mfma<<<1024, 256, 0, stream>>>(uav, wpc, clu_b1, clu_w2, clu_b2, ws + OFF_IMP_U, ws + OFF_WI_U);
        k_regions<<<dim3(32,12), 256, 0, stream>>>(sat, ws + OFF_WI_S, ws + OFF_REG_S);
        k_regions<<<dim3(32,12), 256, 0, stream>>>(uav, ws + OFF_WI_U, ws + OFF_REG_U);
    }

    // similarity MLP: Ai/Bj batched, then fused h1->h2 GEMM, sim, match
    gemm32z<<<dim3(8,24,2), 256, 0, stream>>>(ws + OFF_REG_S, ws + OFF_REG_U,
                                              sim_w1, sim_b1,
                                              ws + OFF_AI, ws + OFF_BJ);
    k_h2f<<<dim3(64,12), 256, 0, stream>>>(ws + OFF_AI, ws + OFF_BJ,
                                           sim_w2, sim_b2, ws + OFF_H2S);
    k_sim<<<64, 256, 0, stream>>>(ws + OFF_H2S, sim_w3, sim_b3, ws + OFF_SIM);
    k_match<<<1, 64, 0, stream>>>(ws + OFF_SIM, (int*)(ws + OFF_IDX));

    // attention pooling: fused z+Wv GEMM, then Wo GEMM, then LN
    k_zwv<<<dim3(8,24), 256, 0, stream>>>(ws + OFF_REG_S, ws + OFF_REG_U,
                                          (const int*)(ws + OFF_IDX),
                                          attn_wv, attn_bv, ws + OFF_T1);
    gemm32<<<dim3(8,24), 256, 0, stream>>>(ws + OFF_T1, 768, attn_wo, 768,
                                           attn_bo, 2.f, 0, ws + OFF_PP, 768, 768);
    k_ln<<<256, 256, 0, stream>>>(ws + OFF_PP, pool_g, pool_b, ws + OFF_POOL);

    // fuse: cat(B, R*D) @ fuse_w -> LN -> relu
    if (big) {
        k_fuse_gemm24<<<dim3(24,12), 256, 0, stream>>>(ws + OFF_POOL, fuse_w, ws + OFF_FP24);
        k_fuse_final24<<<32, 256, 0, stream>>>(ws + OFF_FP24, fuse_b, fuse_g, fuse_bt, out);
    } else {
        k_fuse_gemm<<<dim3(8,12), 256, 0, stream>>>(ws + OFF_POOL, fuse_w, ws + OFF_FP);
        k_fuse_final<<<32, 256, 0, stream>>>(ws + OFF_FP, fuse_b, fuse_g, fuse_bt, out);
    }
}